// Round 5
// baseline (302.196 us; speedup 1.0000x reference)
//
#include <hip/hip_runtime.h>
#include <hip/hip_bf16.h>

#define B_ 4
#define C_ 512
#define T_ 1024
#define SCALE_ 0.125f
#define EPS_ 1e-5f

typedef unsigned short u16;
typedef __attribute__((ext_vector_type(8))) unsigned short u16x8;
typedef __attribute__((ext_vector_type(4))) unsigned short u16x4;
typedef __attribute__((ext_vector_type(8))) short s16x8;
typedef __attribute__((ext_vector_type(4))) float f32x4;

// ws byte offsets
#define QT_OFF    (0x0ull)         // bf16 Qt[B][T][C]   4 MB  (Q pre-scaled by 1/8)
#define KT_OFF    (0x400000ull)    // bf16 Kt[B][T][C]   4 MB
#define V_OFF     (0x800000ull)    // bf16 V [B][C][T]   4 MB
#define XT_OFF    (0xC00000ull)    // bf16 Xt[B][T][C]   4 MB
#define OPART_OFF (0x1000000ull)   // bf16 Opart[B][64][16][512] 4 MB (unnormalized)
#define LP_OFF    (0x2000000ull)   // fp32 lpart [B][8][1024] 128 KB
#define L2P_OFF   (0x2040000ull)   // fp32 l2part[B][8][1024] 128 KB
#define AB_OFF    (0x2080000ull)   // fp32 ab[B][8][2]
#define VSUM_OFF  (0x2090000ull)   // fp32 vsum[B][8][64]
#define O_OFF     (0x20A0000ull)   // bf16 O[B][8][T][64] 4 MB

static __device__ __forceinline__ u16 f2bf(float f) {
  unsigned u = __float_as_uint(f);
  unsigned r = (u + 0x7fff + ((u >> 16) & 1)) >> 16;  // RNE
  return (u16)r;
}
static __device__ __forceinline__ float b2f(u16 x) {
  return __uint_as_float(((unsigned)x) << 16);
}
static __device__ __forceinline__ f32x4 mfma16(s16x8 a, s16x8 b, f32x4 c) {
  return __builtin_amdgcn_mfma_f32_16x16x32_bf16(a, b, c, 0, 0, 0);
}

// ---------------- transpose x -> Xt[b][t][c] bf16 ----------------
__global__ __launch_bounds__(256) void transpose_x(const float* __restrict__ x,
                                                   u16* __restrict__ xt) {
  const int b = blockIdx.z;
  const int t0 = blockIdx.x << 6;
  const int c0 = blockIdx.y << 6;
  const float* __restrict__ X = x + (size_t)b * (C_ * (size_t)T_);
  u16* __restrict__ Xt = xt + (size_t)b * (T_ * (size_t)C_);
  __shared__ float Ts[64][65];
  const int tid = threadIdx.x;
#pragma unroll
  for (int i = 0; i < 4; ++i) {
    const int e = tid + (i << 8);
    const int r = e >> 4, c4 = e & 15;
    const float4 v = *(const float4*)(X + (size_t)(c0 + r) * T_ + t0 + (c4 << 2));
    Ts[r][(c4 << 2) + 0] = v.x; Ts[r][(c4 << 2) + 1] = v.y;
    Ts[r][(c4 << 2) + 2] = v.z; Ts[r][(c4 << 2) + 3] = v.w;
  }
  __syncthreads();
#pragma unroll
  for (int i = 0; i < 2; ++i) {
    const int e = tid + (i << 8);
    const int tt = e >> 3, c8 = e & 7;
    u16x8 o;
#pragma unroll
    for (int j = 0; j < 8; ++j) o[j] = f2bf(Ts[(c8 << 3) + j][tt]);
    *(u16x8*)(Xt + (size_t)(t0 + tt) * C_ + c0 + (c8 << 3)) = o;
  }
}

// ---------------- Qt/Kt = Xt @ W^T  -> [t][o] bf16 (Q scaled by 1/8) --------
__global__ __launch_bounds__(256) void gemm_qkt(const u16* __restrict__ xt,
                                                const float* __restrict__ wq,
                                                const float* __restrict__ wk,
                                                u16* __restrict__ qto,
                                                u16* __restrict__ kto) {
  const int which = blockIdx.z >> 2;
  const int b = blockIdx.z & 3;
  const float* __restrict__ W = which ? wk : wq;
  u16* __restrict__ Y = (which ? kto : qto) + (size_t)b * (T_ * (size_t)C_);
  const u16* __restrict__ A = xt + (size_t)b * (T_ * (size_t)C_);
  const float sc = which ? 1.0f : SCALE_;
  const int m0 = blockIdx.x << 7;  // t
  const int n0 = blockIdx.y << 7;  // o
  __shared__ u16 As[128][40];
  __shared__ u16 Bs[128][40];
  const int tid = threadIdx.x;
  const int w = tid >> 6, lane = tid & 63, lr = lane & 15, lq = lane >> 4;
  const int mw = (w >> 1) << 6, nw = (w & 1) << 6;
  f32x4 acc[4][4] = {};
  for (int k0 = 0; k0 < C_; k0 += 32) {
#pragma unroll
    for (int it = 0; it < 2; ++it) {
      const int e = tid + (it << 8);
      const int r = e >> 2, c4 = e & 3;
      *(u16x8*)&As[r][c4 << 3] =
          *(const u16x8*)(A + (size_t)(m0 + r) * C_ + k0 + (c4 << 3));
      const float* wr = W + (size_t)(n0 + r) * C_ + k0 + (c4 << 3);
      const float4 f0 = *(const float4*)wr;
      const float4 f1 = *(const float4*)(wr + 4);
      u16x8 o;
      o[0] = f2bf(f0.x); o[1] = f2bf(f0.y); o[2] = f2bf(f0.z); o[3] = f2bf(f0.w);
      o[4] = f2bf(f1.x); o[5] = f2bf(f1.y); o[6] = f2bf(f1.z); o[7] = f2bf(f1.w);
      *(u16x8*)&Bs[r][c4 << 3] = o;
    }
    __syncthreads();
    const int ko = lq << 3;
    s16x8 a[4], bb[4];
#pragma unroll
    for (int i = 0; i < 4; ++i) a[i] = *(const s16x8*)&As[mw + (i << 4) + lr][ko];
#pragma unroll
    for (int j = 0; j < 4; ++j) bb[j] = *(const s16x8*)&Bs[nw + (j << 4) + lr][ko];
#pragma unroll
    for (int i = 0; i < 4; ++i)
#pragma unroll
      for (int j = 0; j < 4; ++j) acc[i][j] = mfma16(a[i], bb[j], acc[i][j]);
    __syncthreads();
  }
#pragma unroll
  for (int i = 0; i < 4; ++i) {
    const int row = mw + (i << 4) + (lq << 2);
#pragma unroll
    for (int j = 0; j < 4; ++j) {
      const int col = nw + (j << 4) + lr;
#pragma unroll
      for (int r = 0; r < 4; ++r)
        Y[(size_t)(m0 + row + r) * C_ + n0 + col] = f2bf(acc[i][j][r] * sc);
    }
  }
}

// ---------------- V = Wv @ X  -> [o][t] bf16 ----------------
__global__ __launch_bounds__(256) void gemm_v(const u16* __restrict__ xt,
                                              const float* __restrict__ wv,
                                              u16* __restrict__ vout) {
  const int b = blockIdx.z;
  const int n0 = blockIdx.x << 7;  // t
  const int m0 = blockIdx.y << 7;  // o
  const u16* __restrict__ Bg = xt + (size_t)b * (T_ * (size_t)C_);
  u16* __restrict__ Y = vout + (size_t)b * (C_ * (size_t)T_);
  __shared__ u16 As[128][40];
  __shared__ u16 Bs[128][40];
  const int tid = threadIdx.x;
  const int w = tid >> 6, lane = tid & 63, lr = lane & 15, lq = lane >> 4;
  const int mw = (w >> 1) << 6, nw = (w & 1) << 6;
  f32x4 acc[4][4] = {};
  for (int k0 = 0; k0 < C_; k0 += 32) {
#pragma unroll
    for (int it = 0; it < 2; ++it) {
      const int e = tid + (it << 8);
      const int r = e >> 2, c4 = e & 3;
      const float* wr = wv + (size_t)(m0 + r) * C_ + k0 + (c4 << 3);
      const float4 f0 = *(const float4*)wr;
      const float4 f1 = *(const float4*)(wr + 4);
      u16x8 o;
      o[0] = f2bf(f0.x); o[1] = f2bf(f0.y); o[2] = f2bf(f0.z); o[3] = f2bf(f0.w);
      o[4] = f2bf(f1.x); o[5] = f2bf(f1.y); o[6] = f2bf(f1.z); o[7] = f2bf(f1.w);
      *(u16x8*)&As[r][c4 << 3] = o;
      *(u16x8*)&Bs[r][c4 << 3] =
          *(const u16x8*)(Bg + (size_t)(n0 + r) * C_ + k0 + (c4 << 3));
    }
    __syncthreads();
    const int ko = lq << 3;
    s16x8 a[4], bb[4];
#pragma unroll
    for (int i = 0; i < 4; ++i) a[i] = *(const s16x8*)&As[mw + (i << 4) + lr][ko];
#pragma unroll
    for (int j = 0; j < 4; ++j) bb[j] = *(const s16x8*)&Bs[nw + (j << 4) + lr][ko];
#pragma unroll
    for (int i = 0; i < 4; ++i)
#pragma unroll
      for (int j = 0; j < 4; ++j) acc[i][j] = mfma16(a[i], bb[j], acc[i][j]);
    __syncthreads();
  }
#pragma unroll
  for (int i = 0; i < 4; ++i) {
    const int row = mw + (i << 4) + (lq << 2);
#pragma unroll
    for (int j = 0; j < 4; ++j) {
      const int col = nw + (j << 4) + lr;
#pragma unroll
      for (int r = 0; r < 4; ++r)
        Y[(size_t)(m0 + row + r) * T_ + n0 + col] = f2bf(acc[i][j][r]);
    }
  }
}

// ---------------- vsum[b][g][d] = sum_t V ----------------
__global__ __launch_bounds__(256) void vsum_k(const u16* __restrict__ v,
                                              float* __restrict__ vsum) {
  const int bg = blockIdx.x;  // b*8+g
  const int tid = threadIdx.x;
  const int d = tid >> 2, part = tid & 3;
  const u16* __restrict__ Vr =
      v + ((size_t)(bg >> 3) * C_ + ((bg & 7) << 6) + d) * T_ + (part << 8);
  float s = 0.f;
  for (int t = 0; t < 256; t += 8) {
    const u16x8 x = *(const u16x8*)(Vr + t);
#pragma unroll
    for (int j = 0; j < 8; ++j) s += b2f(x[j]);
  }
  s += __shfl_down(s, 2, 64);
  s += __shfl_down(s, 1, 64);
  if (part == 0) vsum[(bg << 6) + d] = s;
}

// ---------------- fused attention: QK^T -> mix -> exp -> PV ----------------
// 1 block/CU (grid 256), 4 waves, __launch_bounds__(256,1) -> 512-reg budget,
// no spills. Q frags in registers; K staged in LDS in 128t x 256c units with
// register-prefetch pipelining; V read direct (32 independent Oacc chains).
__global__ __launch_bounds__(256, 1) void fused_attn(
    const u16* __restrict__ Qt, const u16* __restrict__ Kt,
    const u16* __restrict__ V, const float* __restrict__ wh,
    u16* __restrict__ Opart, float* __restrict__ lpart,
    float* __restrict__ l2part) {
  const int q16 = blockIdx.x;
  const int b = blockIdx.y;
  const int tid = threadIdx.x;
  const int w = tid >> 6, lane = tid & 63;
  const int lr = lane & 15, quad = lane >> 4;
  const int q0 = q16 << 4;

  const u16* __restrict__ Kb = Kt + (size_t)b * T_ * C_;
  const u16* __restrict__ Vb = V + (size_t)b * C_ * T_;

  __shared__ u16 Ks[128][264];  // one 128t x 256c unit (+8 pad)
  __shared__ float lred[2][4][8][16];

  // Q fragments in registers: (h,kf) -> 16 x s16x8 (64 VGPRs)
  s16x8 qf[16];
  {
    const u16* Qb = Qt + ((size_t)b * T_ + q0 + lr) * C_ + (quad << 3);
#pragma unroll
    for (int h = 0; h < 8; ++h)
#pragma unroll
      for (int kf = 0; kf < 2; ++kf)
        qf[(h << 1) + kf] = *(const s16x8*)(Qb + (h << 6) + (kf << 5));
  }

  f32x4 Oacc[8][4] = {};  // AGPRs
  float lsum[8] = {}, l2sum[8] = {};

  const int srow = tid >> 5;          // 0..7
  const int scol = (tid & 31) << 3;   // 0..248

  // prologue: stage unit 0 (tt=0, ch=0)
  {
    u16x8 kreg[16];
#pragma unroll
    for (int it = 0; it < 16; ++it)
      kreg[it] = *(const u16x8*)(Kb + (size_t)((it << 3) + srow) * C_ + scol);
#pragma unroll
    for (int it = 0; it < 16; ++it)
      *(u16x8*)&Ks[(it << 3) + srow][scol] = kreg[it];
  }
  __syncthreads();

#pragma unroll 1
  for (int tt = 0; tt < 8; ++tt) {
    f32x4 m[8][2] = {};
#pragma unroll 1
    for (int ch = 0; ch < 2; ++ch) {
      const int u = (tt << 1) + ch;
      const int un = u + 1;
      u16x8 kreg[16];
      if (un < 16) {  // prefetch next unit into registers
        const u16* src =
            Kb + (size_t)((un >> 1) << 7) * C_ + ((un & 1) << 8);
#pragma unroll
        for (int it = 0; it < 16; ++it)
          kreg[it] = *(const u16x8*)(src + (size_t)((it << 3) + srow) * C_ + scol);
      }
      // compute: heads ch*4..ch*4+3 from LDS
#pragma unroll
      for (int hh = 0; hh < 4; ++hh) {
        const int h = (ch << 2) + hh;
        f32x4 a0 = {0.f, 0.f, 0.f, 0.f}, a1 = {0.f, 0.f, 0.f, 0.f};
#pragma unroll
        for (int kf = 0; kf < 2; ++kf) {
          const int col = (hh << 6) + (kf << 5) + (quad << 3);
          const s16x8 k0 = *(const s16x8*)&Ks[(w << 5) + lr][col];
          const s16x8 k1 = *(const s16x8*)&Ks[(w << 5) + 16 + lr][col];
          a0 = mfma16(k0, qf[(h << 1) + kf], a0);
          a1 = mfma16(k1, qf[(h << 1) + kf], a1);
        }
#pragma unroll
        for (int g = 0; g < 8; ++g) {
          const float wgh = wh[(g << 3) + h];  // uniform -> SGPR
          m[g][0] += a0 * wgh;
          m[g][1] += a1 * wgh;
        }
      }
      __syncthreads();  // all waves done reading this unit
      if (un < 16) {
#pragma unroll
        for (int it = 0; it < 16; ++it)
          *(u16x8*)&Ks[(it << 3) + srow][scol] = kreg[it];
      }
      __syncthreads();  // next unit visible
    }
    // exp + PV for this 128-t tile (wave's t32 slice)
    const int tb = (tt << 7) + (w << 5);
#pragma unroll
    for (int g = 0; g < 8; ++g) {
      f32x4 e0, e1;
#pragma unroll
      for (int k = 0; k < 4; ++k) {
        e0[k] = __expf(m[g][0][k]);
        e1[k] = __expf(m[g][1][k]);
      }
      lsum[g] += e0[0] + e0[1] + e0[2] + e0[3] + e1[0] + e1[1] + e1[2] + e1[3];
      l2sum[g] += e0[0] * e0[0] + e0[1] * e0[1] + e0[2] * e0[2] + e0[3] * e0[3] +
                  e1[0] * e1[0] + e1[1] * e1[1] + e1[2] * e1[2] + e1[3] * e1[3];
      s16x8 pa;
#pragma unroll
      for (int k = 0; k < 4; ++k) {
        pa[k] = (short)f2bf(e0[k]);
        pa[k + 4] = (short)f2bf(e1[k]);
      }
#pragma unroll
      for (int dt = 0; dt < 4; ++dt) {
        const u16* vr =
            Vb + (size_t)((g << 6) + (dt << 4) + lr) * T_ + tb + (quad << 2);
        const u16x4 v0 = *(const u16x4*)vr;
        const u16x4 v1 = *(const u16x4*)(vr + 16);
        s16x8 vb;
#pragma unroll
        for (int k = 0; k < 4; ++k) {
          vb[k] = (short)v0[k];
          vb[k + 4] = (short)v1[k];
        }
        Oacc[g][dt] = mfma16(pa, vb, Oacc[g][dt]);
      }
    }
  }

  // reduce l across quads (each lane's q = lane&15)
#pragma unroll
  for (int g = 0; g < 8; ++g) {
    lsum[g] += __shfl_xor(lsum[g], 16, 64);
    lsum[g] += __shfl_xor(lsum[g], 32, 64);
    l2sum[g] += __shfl_xor(l2sum[g], 16, 64);
    l2sum[g] += __shfl_xor(l2sum[g], 32, 64);
  }
  // phased cross-wave O reduction in LDS (alias onto Ks)
  float* __restrict__ OredB = (float*)&Ks[0][0];  // [16][520] floats
#pragma unroll 1
  for (int r = 0; r < 4; ++r) {
    if (w == r) {
#pragma unroll
      for (int g = 0; g < 8; ++g)
#pragma unroll
        for (int dt = 0; dt < 4; ++dt)
#pragma unroll
          for (int k = 0; k < 4; ++k) {
            const int q = (quad << 2) + k;
            const int c = (g << 6) + (dt << 4) + lr;
            if (r == 0)
              OredB[q * 520 + c] = Oacc[g][dt][k];
            else
              OredB[q * 520 + c] += Oacc[g][dt][k];
          }
    }
    __syncthreads();
  }
  if (lane < 16) {
#pragma unroll
    for (int g = 0; g < 8; ++g) {
      lred[0][w][g][lane] = lsum[g];
      lred[1][w][g][lane] = l2sum[g];
    }
  }
  __syncthreads();
  u16* __restrict__ Op = Opart + ((size_t)((b << 6) + q16) << 13);
  for (int i = tid; i < 2048; i += 256) {
    const int q = i >> 7, c4 = (i & 127) << 2;
    const float4 v = *(const float4*)&OredB[q * 520 + c4];
    u16x4 o;
    o[0] = f2bf(v.x); o[1] = f2bf(v.y); o[2] = f2bf(v.z); o[3] = f2bf(v.w);
    *(u16x4*)(Op + (q << 9) + c4) = o;
  }
  if (tid < 128) {
    const int g = tid >> 4, qq = tid & 15;
    lpart[(((b << 3) + g) << 10) + q0 + qq] =
        lred[0][0][g][qq] + lred[0][1][g][qq] + lred[0][2][g][qq] +
        lred[0][3][g][qq];
  } else {
    const int g = (tid - 128) >> 4, qq = tid & 15;
    l2part[(((b << 3) + g) << 10) + q0 + qq] =
        lred[1][0][g][qq] + lred[1][1][g][qq] + lred[1][2][g][qq] +
        lred[1][3][g][qq];
  }
}

// ---------------- stats: alpha/beta' per (b,g) ----------------
__global__ __launch_bounds__(256) void reduce_stats(
    const float* __restrict__ lpart, const float* __restrict__ l2part,
    const float* __restrict__ gamma, const float* __restrict__ beta,
    float* __restrict__ ab) {
  const int b = blockIdx.x >> 3, g = blockIdx.x & 7;
  const float* la = lpart + (((b << 3) + g) << 10);
  const float* qa = l2part + (((b << 3) + g) << 10);
  const int tid = threadIdx.x;
  float s = 0.f;
  for (int q = tid; q < 1024; q += 256) {
    const float l = la[q];
    s += qa[q] / (l * l);
  }
#pragma unroll
  for (int off = 32; off; off >>= 1) s += __shfl_xor(s, off, 64);
  __shared__ float red[4];
  if ((tid & 63) == 0) red[tid >> 6] = s;
  __syncthreads();
  if (tid == 0) {
    const float ssq = red[0] + red[1] + red[2] + red[3];
    const float mean = 0.0009765625f;
    const float var = ssq * (1.f / 1048576.f) - mean * mean;
    const float al = gamma[g] * rsqrtf(var + EPS_);
    ab[blockIdx.x * 2] = al;
    ab[blockIdx.x * 2 + 1] = beta[g] - al * mean;
  }
}

// ---------------- normalize + affine -> O bf16 ----------------
__global__ __launch_bounds__(256) void combine(const u16* __restrict__ Opart,
                                               const float* __restrict__ lpart,
                                               const float* __restrict__ ab,
                                               const float* __restrict__ vsum,
                                               u16* __restrict__ O) {
  const int blk = blockIdx.x, b = blk >> 6, q16 = blk & 63;
  const u16* Oa = Opart + ((size_t)((b << 6) + q16) << 13);
  const int tid = threadIdx.x;
  for (int i = tid; i < 2048; i += 256) {
    const int q = i >> 7, c4 = (i & 127) << 2;
    const int g = c4 >> 6, d = c4 & 63;
    const u16x4 a = *(const u16x4*)(Oa + (q << 9) + c4);
    const int qglob = (q16 << 4) + q;
    const float lt = lpart[(((b << 3) + g) << 10) + qglob];
    const float al = ab[(((b << 3) + g) << 1)];
    const float bp2 = ab[(((b << 3) + g) << 1) + 1];
    const float inv = al / lt;
    const float* vs = vsum + (((b << 3) + g) << 6) + d;
    u16x4 o;
    o[0] = f2bf(b2f(a[0]) * inv + bp2 * vs[0]);
    o[1] = f2bf(b2f(a[1]) * inv + bp2 * vs[1]);
    o[2] = f2bf(b2f(a[2]) * inv + bp2 * vs[2]);
    o[3] = f2bf(b2f(a[3]) * inv + bp2 * vs[3]);
    *(u16x4*)(O + ((size_t)(((b << 3) + g) * T_ + qglob) << 6) + d) = o;
  }
}

// ---------------- y = M @ Wp^T + bp,  M gathered from O ----------------
__global__ __launch_bounds__(256) void gemm_proj(const u16* __restrict__ O,
                                                 const float* __restrict__ wp,
                                                 const float* __restrict__ bp,
                                                 float* __restrict__ y) {
  const int b = blockIdx.z;
  const int m0 = blockIdx.y << 7;  // o
  const int n0 = blockIdx.x << 7;  // t
  const u16* __restrict__ Ob = O + (size_t)b * (8 * T_ * 64);
  __shared__ u16 As[128][40];
  __shared__ u16 Bs[128][40];
  const int tid = threadIdx.x;
  const int w = tid >> 6, lane = tid & 63, lr = lane & 15, lq = lane >> 4;
  const int mw = (w >> 1) << 6, nw = (w & 1) << 6;
  f32x4 acc[4][4] = {};
  for (int k0 = 0; k0 < C_; k0 += 32) {
#pragma unroll
    for (int it = 0; it < 2; ++it) {
      const int e = tid + (it << 8);
      const int r = e >> 2, c4 = e & 3;
      const float* wr = wp + (size_t)(m0 + r) * C_ + k0 + (c4 << 3);
      const float4 f0 = *(const float4*)wr;
      const float4 f1 = *(const float4*)(wr + 4);
      u16x8 o;
      o[0] = f2bf(f0.x); o[1] = f2bf(f0.y); o[2] = f2bf(f0.z); o[3] = f2bf(f0.w);
      o[4] = f2bf(f1.x); o[5] = f2bf(f1.y); o[6] = f2bf(f1.z); o[7] = f2bf(f1.w);
      *(u16x8*)&As[r][c4 << 3] = o;
      const int t = n0 + r;
      const int c = k0 + (c4 << 3);
      *(u16x8*)&Bs[r][c4 << 3] =
          *(const u16x8*)(Ob + (size_t)(t >> 7) * (T_ * 64) +
                          (size_t)(((t & 127) << 3) + (c >> 6)) * 64 + (c & 63));
    }
    __syncthreads();
    const int ko = lq << 3;
    s16x8 a[4], bb[4];
#pragma unroll
    for (int i = 0; i < 4; ++i) a[i] = *(const s16x8*)&As[mw + (i << 4) + lr][ko];
#pragma unroll
    for (int j = 0; j < 4; ++j) bb[j] = *(const s16x8*)&Bs[nw + (j << 4) + lr][ko];
#pragma unroll
    for (int i = 0; i < 4; ++i)
#pragma unroll
      for (int j = 0; j < 4; ++j) acc[i][j] = mfma16(a[i], bb[j], acc[i][j]);
    __syncthreads();
  }
#pragma unroll
  for (int i = 0; i < 4; ++i) {
    const int row = mw + (i << 4) + (lq << 2);
#pragma unroll
    for (int j = 0; j < 4; ++j) {
      const int col = nw + (j << 4) + lr;
#pragma unroll
      for (int r = 0; r < 4; ++r)
        y[(size_t)b * (C_ * (size_t)T_) + (size_t)(m0 + row + r) * T_ + n0 + col] =
            acc[i][j][r] + bp[m0 + row + r];
    }
  }
}

extern "C" void kernel_launch(void* const* d_in, const int* in_sizes, int n_in,
                              void* d_out, int out_size, void* d_ws,
                              size_t ws_size, hipStream_t stream) {
  const float* x = (const float*)d_in[0];
  const float* wq = (const float*)d_in[1];
  const float* wk = (const float*)d_in[2];
  const float* wv = (const float*)d_in[3];
  const float* wh = (const float*)d_in[4];
  const float* gm = (const float*)d_in[5];
  const float* bt = (const float*)d_in[6];
  const float* wp = (const float*)d_in[7];
  const float* bp = (const float*)d_in[8];
  float* y = (float*)d_out;
  char* wsb = (char*)d_ws;

  u16* Qt = (u16*)(wsb + QT_OFF);
  u16* Kt = (u16*)(wsb + KT_OFF);
  u16* V = (u16*)(wsb + V_OFF);
  u16* Xt = (u16*)(wsb + XT_OFF);
  u16* Opart = (u16*)(wsb + OPART_OFF);
  float* lpart = (float*)(wsb + LP_OFF);
  float* l2part = (float*)(wsb + L2P_OFF);
  float* ab = (float*)(wsb + AB_OFF);
  float* vsum = (float*)(wsb + VSUM_OFF);
  u16* Og = (u16*)(wsb + O_OFF);

  transpose_x<<<dim3(16, 8, 4), 256, 0, stream>>>(x, Xt);
  gemm_qkt<<<dim3(8, 4, 8), 256, 0, stream>>>(Xt, wq, wk, Qt, Kt);
  gemm_v<<<dim3(8, 4, 4), 256, 0, stream>>>(Xt, wv, V);
  vsum_k<<<dim3(32), 256, 0, stream>>>(V, vsum);
  fused_attn<<<dim3(64, 4), 256, 0, stream>>>(Qt, Kt, V, wh, Opart, lpart,
                                              l2part);
  reduce_stats<<<dim3(32), 256, 0, stream>>>(lpart, l2part, gm, bt, ab);
  combine<<<dim3(256), 256, 0, stream>>>(Opart, lpart, ab, vsum, Og);
  gemm_proj<<<dim3(8, 4, 4), 256, 0, stream>>>(Og, wp, bp, y);
}

// Round 7
// 287.085 us; speedup vs baseline: 1.0526x; 1.0526x over previous
//
#include <hip/hip_runtime.h>
#include <hip/hip_bf16.h>

#define B_ 4
#define C_ 512
#define T_ 1024
#define SCALE_ 0.125f
#define EPS_ 1e-5f

typedef unsigned short u16;
typedef __attribute__((ext_vector_type(8))) unsigned short u16x8;
typedef __attribute__((ext_vector_type(4))) unsigned short u16x4;
typedef __attribute__((ext_vector_type(8))) short s16x8;
typedef __attribute__((ext_vector_type(4))) float f32x4;

// ws byte offsets
#define QT_OFF    (0x0ull)         // bf16 Qt[B][T][C]   4 MB  (Q pre-scaled by 1/8)
#define KT_OFF    (0x400000ull)    // bf16 Kt[B][T][C]   4 MB
#define V_OFF     (0x800000ull)    // bf16 V [B][C][T]   4 MB
#define XT_OFF    (0xC00000ull)    // bf16 Xt[B][T][C]   4 MB
#define O_OFF     (0x1000000ull)   // bf16 O[B][8][T][64] 4 MB (softmax-normalized, pre-affine)
#define PSSQ_OFF  (0x1400000ull)   // fp32 pssq[B*8][64] 8 KB
#define AB_OFF    (0x1410000ull)   // fp32 ab[B][8][2]
#define VSUM_OFF  (0x1420000ull)   // fp32 vsum[B][8][64] 8 KB
#define BIAS2_OFF (0x1430000ull)   // fp32 bias2[B][8][512] 64 KB

static __device__ __forceinline__ u16 f2bf(float f) {
  unsigned u = __float_as_uint(f);
  unsigned r = (u + 0x7fff + ((u >> 16) & 1)) >> 16;  // RNE
  return (u16)r;
}
static __device__ __forceinline__ float b2f(u16 x) {
  return __uint_as_float(((unsigned)x) << 16);
}
static __device__ __forceinline__ f32x4 mfma16(s16x8 a, s16x8 b, f32x4 c) {
  return __builtin_amdgcn_mfma_f32_16x16x32_bf16(a, b, c, 0, 0, 0);
}

// ---------------- transpose x -> Xt[b][t][c] bf16 ----------------
__global__ __launch_bounds__(256) void transpose_x(const float* __restrict__ x,
                                                   u16* __restrict__ xt) {
  const int b = blockIdx.z;
  const int t0 = blockIdx.x << 6;
  const int c0 = blockIdx.y << 6;
  const float* __restrict__ X = x + (size_t)b * (C_ * (size_t)T_);
  u16* __restrict__ Xt = xt + (size_t)b * (T_ * (size_t)C_);
  __shared__ float Ts[64][65];
  const int tid = threadIdx.x;
#pragma unroll
  for (int i = 0; i < 4; ++i) {
    const int e = tid + (i << 8);
    const int r = e >> 4, c4 = e & 15;
    const float4 v = *(const float4*)(X + (size_t)(c0 + r) * T_ + t0 + (c4 << 2));
    Ts[r][(c4 << 2) + 0] = v.x; Ts[r][(c4 << 2) + 1] = v.y;
    Ts[r][(c4 << 2) + 2] = v.z; Ts[r][(c4 << 2) + 3] = v.w;
  }
  __syncthreads();
#pragma unroll
  for (int i = 0; i < 2; ++i) {
    const int e = tid + (i << 8);
    const int tt = e >> 3, c8 = e & 7;
    u16x8 o;
#pragma unroll
    for (int j = 0; j < 8; ++j) o[j] = f2bf(Ts[(c8 << 3) + j][tt]);
    *(u16x8*)(Xt + (size_t)(t0 + tt) * C_ + c0 + (c8 << 3)) = o;
  }
}

// ---------------- Qt/Kt = Xt @ W^T  -> [t][o] bf16 (Q scaled by 1/8) --------
__global__ __launch_bounds__(256) void gemm_qkt(const u16* __restrict__ xt,
                                                const float* __restrict__ wq,
                                                const float* __restrict__ wk,
                                                u16* __restrict__ qto,
                                                u16* __restrict__ kto) {
  const int which = blockIdx.z >> 2;
  const int b = blockIdx.z & 3;
  const float* __restrict__ W = which ? wk : wq;
  u16* __restrict__ Y = (which ? kto : qto) + (size_t)b * (T_ * (size_t)C_);
  const u16* __restrict__ A = xt + (size_t)b * (T_ * (size_t)C_);
  const float sc = which ? 1.0f : SCALE_;
  const int m0 = blockIdx.x << 7;  // t
  const int n0 = blockIdx.y << 7;  // o
  __shared__ u16 As[128][40];
  __shared__ u16 Bs[128][40];
  const int tid = threadIdx.x;
  const int w = tid >> 6, lane = tid & 63, lr = lane & 15, lq = lane >> 4;
  const int mw = (w >> 1) << 6, nw = (w & 1) << 6;
  f32x4 acc[4][4] = {};
  for (int k0 = 0; k0 < C_; k0 += 32) {
#pragma unroll
    for (int it = 0; it < 2; ++it) {
      const int e = tid + (it << 8);
      const int r = e >> 2, c4 = e & 3;
      *(u16x8*)&As[r][c4 << 3] =
          *(const u16x8*)(A + (size_t)(m0 + r) * C_ + k0 + (c4 << 3));
      const float* wr = W + (size_t)(n0 + r) * C_ + k0 + (c4 << 3);
      const float4 f0 = *(const float4*)wr;
      const float4 f1 = *(const float4*)(wr + 4);
      u16x8 o;
      o[0] = f2bf(f0.x); o[1] = f2bf(f0.y); o[2] = f2bf(f0.z); o[3] = f2bf(f0.w);
      o[4] = f2bf(f1.x); o[5] = f2bf(f1.y); o[6] = f2bf(f1.z); o[7] = f2bf(f1.w);
      *(u16x8*)&Bs[r][c4 << 3] = o;
    }
    __syncthreads();
    const int ko = lq << 3;
    s16x8 a[4], bb[4];
#pragma unroll
    for (int i = 0; i < 4; ++i) a[i] = *(const s16x8*)&As[mw + (i << 4) + lr][ko];
#pragma unroll
    for (int j = 0; j < 4; ++j) bb[j] = *(const s16x8*)&Bs[nw + (j << 4) + lr][ko];
#pragma unroll
    for (int i = 0; i < 4; ++i)
#pragma unroll
      for (int j = 0; j < 4; ++j) acc[i][j] = mfma16(a[i], bb[j], acc[i][j]);
    __syncthreads();
  }
#pragma unroll
  for (int i = 0; i < 4; ++i) {
    const int row = mw + (i << 4) + (lq << 2);
#pragma unroll
    for (int j = 0; j < 4; ++j) {
      const int col = nw + (j << 4) + lr;
#pragma unroll
      for (int r = 0; r < 4; ++r)
        Y[(size_t)(m0 + row + r) * C_ + n0 + col] = f2bf(acc[i][j][r] * sc);
    }
  }
}

// ---------------- V = Wv @ X  -> [o][t] bf16 ----------------
__global__ __launch_bounds__(256) void gemm_v(const u16* __restrict__ xt,
                                              const float* __restrict__ wv,
                                              u16* __restrict__ vout) {
  const int b = blockIdx.z;
  const int n0 = blockIdx.x << 7;  // t
  const int m0 = blockIdx.y << 7;  // o
  const u16* __restrict__ Bg = xt + (size_t)b * (T_ * (size_t)C_);
  u16* __restrict__ Y = vout + (size_t)b * (C_ * (size_t)T_);
  __shared__ u16 As[128][40];
  __shared__ u16 Bs[128][40];
  const int tid = threadIdx.x;
  const int w = tid >> 6, lane = tid & 63, lr = lane & 15, lq = lane >> 4;
  const int mw = (w >> 1) << 6, nw = (w & 1) << 6;
  f32x4 acc[4][4] = {};
  for (int k0 = 0; k0 < C_; k0 += 32) {
#pragma unroll
    for (int it = 0; it < 2; ++it) {
      const int e = tid + (it << 8);
      const int r = e >> 2, c4 = e & 3;
      const float* wr = wv + (size_t)(m0 + r) * C_ + k0 + (c4 << 3);
      const float4 f0 = *(const float4*)wr;
      const float4 f1 = *(const float4*)(wr + 4);
      u16x8 o;
      o[0] = f2bf(f0.x); o[1] = f2bf(f0.y); o[2] = f2bf(f0.z); o[3] = f2bf(f0.w);
      o[4] = f2bf(f1.x); o[5] = f2bf(f1.y); o[6] = f2bf(f1.z); o[7] = f2bf(f1.w);
      *(u16x8*)&As[r][c4 << 3] = o;
      *(u16x8*)&Bs[r][c4 << 3] =
          *(const u16x8*)(Bg + (size_t)(n0 + r) * C_ + k0 + (c4 << 3));
    }
    __syncthreads();
    const int ko = lq << 3;
    s16x8 a[4], bb[4];
#pragma unroll
    for (int i = 0; i < 4; ++i) a[i] = *(const s16x8*)&As[mw + (i << 4) + lr][ko];
#pragma unroll
    for (int j = 0; j < 4; ++j) bb[j] = *(const s16x8*)&Bs[nw + (j << 4) + lr][ko];
#pragma unroll
    for (int i = 0; i < 4; ++i)
#pragma unroll
      for (int j = 0; j < 4; ++j) acc[i][j] = mfma16(a[i], bb[j], acc[i][j]);
    __syncthreads();
  }
#pragma unroll
  for (int i = 0; i < 4; ++i) {
    const int row = mw + (i << 4) + (lq << 2);
#pragma unroll
    for (int j = 0; j < 4; ++j) {
      const int col = nw + (j << 4) + lr;
#pragma unroll
      for (int r = 0; r < 4; ++r)
        Y[(size_t)(m0 + row + r) * T_ + n0 + col] = f2bf(acc[i][j][r]);
    }
  }
}

// ---------------- vsum[b][g][d] = sum_t V ----------------
__global__ __launch_bounds__(256) void vsum_k(const u16* __restrict__ v,
                                              float* __restrict__ vsum) {
  const int bg = blockIdx.x;  // b*8+g
  const int tid = threadIdx.x;
  const int d = tid >> 2, part = tid & 3;
  const u16* __restrict__ Vr =
      v + ((size_t)(bg >> 3) * C_ + ((bg & 7) << 6) + d) * T_ + (part << 8);
  float s = 0.f;
  for (int t = 0; t < 256; t += 8) {
    const u16x8 x = *(const u16x8*)(Vr + t);
#pragma unroll
    for (int j = 0; j < 8; ++j) s += b2f(x[j]);
  }
  s += __shfl_down(s, 2, 64);
  s += __shfl_down(s, 1, 64);
  if (part == 0) vsum[(bg << 6) + d] = s;
}

// ---------------- fused attention: QK^T -> mix -> exp -> PV -> /l ----------
__global__ __launch_bounds__(256, 2) void fused_attn(
    const u16* __restrict__ Qt, const u16* __restrict__ Kt,
    const u16* __restrict__ V, const float* __restrict__ wh,
    u16* __restrict__ O, float* __restrict__ pssq) {
  const int q16 = blockIdx.x;
  const int gh = blockIdx.y;  // 0,1
  const int b = blockIdx.z;
  const int tid = threadIdx.x;
  const int w = tid >> 6, lane = tid & 63;
  const int lr = lane & 15, quad = lane >> 4;
  const int q0 = q16 << 4;

  const u16* __restrict__ Kb = Kt + (size_t)b * T_ * C_;
  const u16* __restrict__ Vb = V + ((size_t)b * C_ + (gh << 8)) * T_;

  __shared__ u16 Qs[16][520];
  __shared__ float Ored[16][264];
  __shared__ float lredA[4][4][16];
  __shared__ float lredB[4][4][16];
  __shared__ float lT[4][16];

  {
    const u16* Qb = Qt + ((size_t)b * T_ + q0) * C_;
    for (int i = tid; i < 1024; i += 256) {
      const int r = i >> 6, c8 = i & 63;
      *(u16x8*)&Qs[r][c8 << 3] = *(const u16x8*)(Qb + (size_t)r * C_ + (c8 << 3));
    }
  }
  __syncthreads();

  f32x4 Oacc[4][4] = {};
  float lsum[4] = {}, l2sum[4] = {};

#pragma unroll 1
  for (int sl = 0; sl < 8; ++sl) {
    const int tb = (sl << 7) + (w << 5);
    f32x4 m[4][2] = {};
#pragma unroll 2
    for (int h = 0; h < 8; ++h) {
      f32x4 a0 = {0.f, 0.f, 0.f, 0.f}, a1 = {0.f, 0.f, 0.f, 0.f};
#pragma unroll
      for (int kf = 0; kf < 2; ++kf) {
        const int co = (h << 6) + (kf << 5) + (quad << 3);
        const s16x8 qfr = *(const s16x8*)&Qs[lr][co];
        const s16x8 k0 = *(const s16x8*)(Kb + (size_t)(tb + lr) * C_ + co);
        const s16x8 k1 = *(const s16x8*)(Kb + (size_t)(tb + 16 + lr) * C_ + co);
        a0 = mfma16(k0, qfr, a0);
        a1 = mfma16(k1, qfr, a1);
      }
#pragma unroll
      for (int g = 0; g < 4; ++g) {
        const float wgh = wh[(((gh << 2) + g) << 3) + h];  // uniform -> SGPR
        m[g][0] += a0 * wgh;
        m[g][1] += a1 * wgh;
      }
    }
#pragma unroll
    for (int g = 0; g < 4; ++g) {
      f32x4 e0, e1;
#pragma unroll
      for (int k = 0; k < 4; ++k) {
        e0[k] = __expf(m[g][0][k]);
        e1[k] = __expf(m[g][1][k]);
      }
      lsum[g] += e0[0] + e0[1] + e0[2] + e0[3] + e1[0] + e1[1] + e1[2] + e1[3];
      l2sum[g] += e0[0] * e0[0] + e0[1] * e0[1] + e0[2] * e0[2] + e0[3] * e0[3] +
                  e1[0] * e1[0] + e1[1] * e1[1] + e1[2] * e1[2] + e1[3] * e1[3];
      s16x8 pa;
#pragma unroll
      for (int k = 0; k < 4; ++k) {
        pa[k] = (short)f2bf(e0[k]);
        pa[k + 4] = (short)f2bf(e1[k]);
      }
#pragma unroll
      for (int dt = 0; dt < 4; ++dt) {
        const u16* vr =
            Vb + (size_t)((g << 6) + (dt << 4) + lr) * T_ + tb + (quad << 2);
        const u16x4 v0 = *(const u16x4*)vr;
        const u16x4 v1 = *(const u16x4*)(vr + 16);
        s16x8 vb;
#pragma unroll
        for (int k = 0; k < 4; ++k) {
          vb[k] = (short)v0[k];
          vb[k + 4] = (short)v1[k];
        }
        Oacc[g][dt] = mfma16(pa, vb, Oacc[g][dt]);
      }
    }
  }

  // reduce l across quads (lane's q = lane&15)
#pragma unroll
  for (int g = 0; g < 4; ++g) {
    lsum[g] += __shfl_xor(lsum[g], 16, 64);
    lsum[g] += __shfl_xor(lsum[g], 32, 64);
    l2sum[g] += __shfl_xor(l2sum[g], 16, 64);
    l2sum[g] += __shfl_xor(l2sum[g], 32, 64);
  }
  // phased cross-wave O reduction in LDS
#pragma unroll 1
  for (int r = 0; r < 4; ++r) {
    if (w == r) {
#pragma unroll
      for (int g = 0; g < 4; ++g)
#pragma unroll
        for (int dt = 0; dt < 4; ++dt)
#pragma unroll
          for (int k = 0; k < 4; ++k) {
            const int q = (quad << 2) + k;
            const int c = (g << 6) + (dt << 4) + lr;
            if (r == 0)
              Ored[q][c] = Oacc[g][dt][k];
            else
              Ored[q][c] += Oacc[g][dt][k];
          }
    }
    __syncthreads();
  }
  if (lane < 16) {
#pragma unroll
    for (int g = 0; g < 4; ++g) {
      lredA[w][g][lane] = lsum[g];
      lredB[w][g][lane] = l2sum[g];
    }
  }
  __syncthreads();
  if (tid < 64) {
    const int g = tid >> 4, qq = tid & 15;
    const float l = lredA[0][g][qq] + lredA[1][g][qq] + lredA[2][g][qq] +
                    lredA[3][g][qq];
    const float l2v = lredB[0][g][qq] + lredB[1][g][qq] + lredB[2][g][qq] +
                      lredB[3][g][qq];
    lT[g][qq] = 1.f / l;
    float v = l2v / (l * l);
    v += __shfl_xor(v, 1, 64);
    v += __shfl_xor(v, 2, 64);
    v += __shfl_xor(v, 4, 64);
    v += __shfl_xor(v, 8, 64);
    if (qq == 0) pssq[(((b << 3) + (gh << 2) + g) << 6) + q16] = v;
  }
  __syncthreads();
  // write O[b][gh*4+g][q0+q][d] = Ored/l  (pre-affine)
  for (int i = tid; i < 1024; i += 256) {
    const int q = i >> 6, c4 = (i & 63) << 2;
    const int g = c4 >> 6, d = c4 & 63;
    const float inv = lT[g][q];
    u16x4 o;
#pragma unroll
    for (int j = 0; j < 4; ++j) o[j] = f2bf(Ored[q][c4 + j] * inv);
    *(u16x4*)(O + ((size_t)(((b << 3) + (gh << 2) + g) * T_ + q0 + q) << 6) + d) = o;
  }
}

// ---------------- stats: alpha/beta' per (b,g) ----------------
__global__ __launch_bounds__(64) void reduce_stats(
    const float* __restrict__ pssq, const float* __restrict__ gamma,
    const float* __restrict__ beta, float* __restrict__ ab) {
  const int bg = blockIdx.x;  // b*8+g
  const int g = bg & 7;
  const int tid = threadIdx.x;
  float s = pssq[(bg << 6) + tid];
#pragma unroll
  for (int off = 32; off; off >>= 1) s += __shfl_xor(s, off, 64);
  if (tid == 0) {
    const float mean = 0.0009765625f;
    const float var = s * (1.f / 1048576.f) - mean * mean;
    const float al = gamma[g] * rsqrtf(var + EPS_);
    ab[bg * 2] = al;
    ab[bg * 2 + 1] = beta[g] - al * mean;
  }
}

// -------- bias2[b][g][o] = bp[o] + bt2[b,g] * sum_d vsum[b,g,d]*wsum[o][d]
// wsum[o][d] = sum_{j=0..7} wp[o][j*64+d]  (d = c&63 repeats every 64 cols)
__global__ __launch_bounds__(256) void bias2_k(const float* __restrict__ wp,
                                               const float* __restrict__ bp,
                                               const float* __restrict__ ab,
                                               const float* __restrict__ vsum,
                                               float* __restrict__ bias2) {
  const int idx = (blockIdx.x << 8) + threadIdx.x;  // 16384 = B*8*512
  const int b = idx >> 12, g = (idx >> 9) & 7, o = idx & 511;
  const float bt2 = ab[(((b << 3) + g) << 1) + 1];
  const float* wr = wp + (size_t)o * C_;
  const float* vs = vsum + (((b << 3) + g) << 6);
  float acc = 0.f;
#pragma unroll
  for (int d = 0; d < 64; d += 4) {
    const float4 vv4 = *(const float4*)(vs + d);
    float4 ws4 = {0.f, 0.f, 0.f, 0.f};
#pragma unroll
    for (int j = 0; j < 8; ++j) {
      const float4 wv4 = *(const float4*)(wr + (j << 6) + d);
      ws4.x += wv4.x; ws4.y += wv4.y; ws4.z += wv4.z; ws4.w += wv4.w;
    }
    acc += ws4.x * vv4.x + ws4.y * vv4.y + ws4.z * vv4.z + ws4.w * vv4.w;
  }
  bias2[(((b << 3) + g) << 9) + o] = bp[o] + bt2 * acc;
}

// ---------------- y = al[b,g(t)]*(Mnorm @ Wp^T) + bias2[b][g(t)][o] --------
// g(t) = t>>7 = blockIdx.x (128-wide aligned t tiles) -> uniform per block.
__global__ __launch_bounds__(256) void gemm_proj(const u16* __restrict__ O,
                                                 const float* __restrict__ wp,
                                                 const float* __restrict__ ab,
                                                 const float* __restrict__ bias2,
                                                 float* __restrict__ y) {
  const int b = blockIdx.z;
  const int m0 = blockIdx.y << 7;  // o
  const int n0 = blockIdx.x << 7;  // t
  const int gidx = blockIdx.x;     // g = t>>7, uniform for this block
  const u16* __restrict__ Ob = O + (size_t)b * (8 * T_ * 64);
  __shared__ u16 As[128][40];
  __shared__ u16 Bs[128][40];
  const int tid = threadIdx.x;
  const int w = tid >> 6, lane = tid & 63, lr = lane & 15, lq = lane >> 4;
  const int mw = (w >> 1) << 6, nw = (w & 1) << 6;
  f32x4 acc[4][4] = {};
  for (int k0 = 0; k0 < C_; k0 += 32) {
#pragma unroll
    for (int it = 0; it < 2; ++it) {
      const int e = tid + (it << 8);
      const int r = e >> 2, c4 = e & 3;
      const float* wr = wp + (size_t)(m0 + r) * C_ + k0 + (c4 << 3);
      const float4 f0 = *(const float4*)wr;
      const float4 f1 = *(const float4*)(wr + 4);
      u16x8 o;
      o[0] = f2bf(f0.x); o[1] = f2bf(f0.y); o[2] = f2bf(f0.z); o[3] = f2bf(f0.w);
      o[4] = f2bf(f1.x); o[5] = f2bf(f1.y); o[6] = f2bf(f1.z); o[7] = f2bf(f1.w);
      *(u16x8*)&As[r][c4 << 3] = o;
      const int t = n0 + r;
      const int c = k0 + (c4 << 3);
      *(u16x8*)&Bs[r][c4 << 3] =
          *(const u16x8*)(Ob + (size_t)(t >> 7) * (T_ * 64) +
                          (size_t)(((t & 127) << 3) + (c >> 6)) * 64 + (c & 63));
    }
    __syncthreads();
    const int ko = lq << 3;
    s16x8 a[4], bb[4];
#pragma unroll
    for (int i = 0; i < 4; ++i) a[i] = *(const s16x8*)&As[mw + (i << 4) + lr][ko];
#pragma unroll
    for (int j = 0; j < 4; ++j) bb[j] = *(const s16x8*)&Bs[nw + (j << 4) + lr][ko];
#pragma unroll
    for (int i = 0; i < 4; ++i)
#pragma unroll
      for (int j = 0; j < 4; ++j) acc[i][j] = mfma16(a[i], bb[j], acc[i][j]);
    __syncthreads();
  }
  const float al = ab[(((b << 3) + gidx) << 1)];
  const float* __restrict__ b2 = bias2 + (((b << 3) + gidx) << 9);
#pragma unroll
  for (int i = 0; i < 4; ++i) {
    const int row = mw + (i << 4) + (lq << 2);
#pragma unroll
    for (int j = 0; j < 4; ++j) {
      const int col = nw + (j << 4) + lr;
#pragma unroll
      for (int r = 0; r < 4; ++r)
        y[(size_t)b * (C_ * (size_t)T_) + (size_t)(m0 + row + r) * T_ + n0 + col] =
            acc[i][j][r] * al + b2[m0 + row + r];
    }
  }
}

extern "C" void kernel_launch(void* const* d_in, const int* in_sizes, int n_in,
                              void* d_out, int out_size, void* d_ws,
                              size_t ws_size, hipStream_t stream) {
  const float* x = (const float*)d_in[0];
  const float* wq = (const float*)d_in[1];
  const float* wk = (const float*)d_in[2];
  const float* wv = (const float*)d_in[3];
  const float* wh = (const float*)d_in[4];
  const float* gm = (const float*)d_in[5];
  const float* bt = (const float*)d_in[6];
  const float* wp = (const float*)d_in[7];
  const float* bp = (const float*)d_in[8];
  float* y = (float*)d_out;
  char* wsb = (char*)d_ws;

  u16* Qt = (u16*)(wsb + QT_OFF);
  u16* Kt = (u16*)(wsb + KT_OFF);
  u16* V = (u16*)(wsb + V_OFF);
  u16* Xt = (u16*)(wsb + XT_OFF);
  u16* Og = (u16*)(wsb + O_OFF);
  float* pssq = (float*)(wsb + PSSQ_OFF);
  float* ab = (float*)(wsb + AB_OFF);
  float* vsum = (float*)(wsb + VSUM_OFF);
  float* bias2 = (float*)(wsb + BIAS2_OFF);

  transpose_x<<<dim3(16, 8, 4), 256, 0, stream>>>(x, Xt);
  gemm_qkt<<<dim3(8, 4, 8), 256, 0, stream>>>(Xt, wq, wk, Qt, Kt);
  gemm_v<<<dim3(8, 4, 4), 256, 0, stream>>>(Xt, wv, V);
  vsum_k<<<dim3(32), 256, 0, stream>>>(V, vsum);
  fused_attn<<<dim3(64, 2, 4), 256, 0, stream>>>(Qt, Kt, V, wh, Og, pssq);
  reduce_stats<<<dim3(32), 64, 0, stream>>>(pssq, gm, bt, ab);
  bias2_k<<<dim3(64), 256, 0, stream>>>(wp, bp, ab, vsum, bias2);
  gemm_proj<<<dim3(8, 4, 4), 256, 0, stream>>>(Og, wp, ab, bias2, y);
}

// Round 8
// 286.868 us; speedup vs baseline: 1.0534x; 1.0008x over previous
//
#include <hip/hip_runtime.h>
#include <hip/hip_bf16.h>

#define B_ 4
#define C_ 512
#define T_ 1024
#define SCALE_ 0.125f
#define EPS_ 1e-5f

typedef unsigned short u16;
typedef __attribute__((ext_vector_type(8))) unsigned short u16x8;
typedef __attribute__((ext_vector_type(4))) unsigned short u16x4;
typedef __attribute__((ext_vector_type(8))) short s16x8;
typedef __attribute__((ext_vector_type(4))) float f32x4;

// ws byte offsets
#define QT_OFF    (0x0ull)         // bf16 Qt[B][T][C]   4 MB  (Q pre-scaled by 1/8)
#define KT_OFF    (0x400000ull)    // bf16 Kt[B][T][C]   4 MB
#define V_OFF     (0x800000ull)    // bf16 V [B][C][T]   4 MB
#define XT_OFF    (0xC00000ull)    // bf16 Xt[B][T][C]   4 MB
#define O_OFF     (0x1000000ull)   // bf16 O[B][8][T][64] 4 MB (softmax-normalized, pre-affine)
#define PSSQ_OFF  (0x1400000ull)   // fp32 pssq[B*8][64] 8 KB
#define AB_OFF    (0x1410000ull)   // fp32 ab[B][8][2]
#define VSUM_OFF  (0x1420000ull)   // fp32 vsum[B][8][64] 8 KB
#define BIAS2_OFF (0x1430000ull)   // fp32 bias2[B][8][512] 64 KB

static __device__ __forceinline__ u16 f2bf(float f) {
  unsigned u = __float_as_uint(f);
  unsigned r = (u + 0x7fff + ((u >> 16) & 1)) >> 16;  // RNE
  return (u16)r;
}
static __device__ __forceinline__ float b2f(u16 x) {
  return __uint_as_float(((unsigned)x) << 16);
}
static __device__ __forceinline__ f32x4 mfma16(s16x8 a, s16x8 b, f32x4 c) {
  return __builtin_amdgcn_mfma_f32_16x16x32_bf16(a, b, c, 0, 0, 0);
}

// ---------------- transpose x -> Xt[b][t][c] bf16 ----------------
__global__ __launch_bounds__(256) void transpose_x(const float* __restrict__ x,
                                                   u16* __restrict__ xt) {
  const int b = blockIdx.z;
  const int t0 = blockIdx.x << 6;
  const int c0 = blockIdx.y << 6;
  const float* __restrict__ X = x + (size_t)b * (C_ * (size_t)T_);
  u16* __restrict__ Xt = xt + (size_t)b * (T_ * (size_t)C_);
  __shared__ float Ts[64][65];
  const int tid = threadIdx.x;
#pragma unroll
  for (int i = 0; i < 4; ++i) {
    const int e = tid + (i << 8);
    const int r = e >> 4, c4 = e & 15;
    const float4 v = *(const float4*)(X + (size_t)(c0 + r) * T_ + t0 + (c4 << 2));
    Ts[r][(c4 << 2) + 0] = v.x; Ts[r][(c4 << 2) + 1] = v.y;
    Ts[r][(c4 << 2) + 2] = v.z; Ts[r][(c4 << 2) + 3] = v.w;
  }
  __syncthreads();
#pragma unroll
  for (int i = 0; i < 2; ++i) {
    const int e = tid + (i << 8);
    const int tt = e >> 3, c8 = e & 7;
    u16x8 o;
#pragma unroll
    for (int j = 0; j < 8; ++j) o[j] = f2bf(Ts[(c8 << 3) + j][tt]);
    *(u16x8*)(Xt + (size_t)(t0 + tt) * C_ + c0 + (c8 << 3)) = o;
  }
}

// ------- Qt/Kt = Xt @ W^T -> [t][o] bf16 (Q scaled by 1/8), 64x64 tiles -----
__global__ __launch_bounds__(256) void gemm_qkt(const u16* __restrict__ xt,
                                                const float* __restrict__ wq,
                                                const float* __restrict__ wk,
                                                u16* __restrict__ qto,
                                                u16* __restrict__ kto) {
  const int which = blockIdx.z >> 2;
  const int b = blockIdx.z & 3;
  const float* __restrict__ W = which ? wk : wq;
  u16* __restrict__ Y = (which ? kto : qto) + (size_t)b * (T_ * (size_t)C_);
  const u16* __restrict__ A = xt + (size_t)b * (T_ * (size_t)C_);
  const float sc = which ? 1.0f : SCALE_;
  const int m0 = blockIdx.x << 6;  // t
  const int n0 = blockIdx.y << 6;  // o
  __shared__ u16 As[64][72];
  __shared__ u16 Bs[64][72];
  const int tid = threadIdx.x;
  const int w = tid >> 6, lane = tid & 63, lr = lane & 15, lq = lane >> 4;
  const int mw = (w >> 1) << 5, nw = (w & 1) << 5;
  f32x4 acc[2][2] = {};
  for (int k0 = 0; k0 < C_; k0 += 64) {
#pragma unroll
    for (int it = 0; it < 2; ++it) {
      const int e = tid + (it << 8);
      const int r = e >> 3, c8 = e & 7;
      *(u16x8*)&As[r][c8 << 3] =
          *(const u16x8*)(A + (size_t)(m0 + r) * C_ + k0 + (c8 << 3));
      const float* wr = W + (size_t)(n0 + r) * C_ + k0 + (c8 << 3);
      const float4 f0 = *(const float4*)wr;
      const float4 f1 = *(const float4*)(wr + 4);
      u16x8 o;
      o[0] = f2bf(f0.x); o[1] = f2bf(f0.y); o[2] = f2bf(f0.z); o[3] = f2bf(f0.w);
      o[4] = f2bf(f1.x); o[5] = f2bf(f1.y); o[6] = f2bf(f1.z); o[7] = f2bf(f1.w);
      *(u16x8*)&Bs[r][c8 << 3] = o;
    }
    __syncthreads();
#pragma unroll
    for (int kf = 0; kf < 2; ++kf) {
      const int ko = (kf << 5) + (lq << 3);
      s16x8 a[2], bb[2];
#pragma unroll
      for (int i = 0; i < 2; ++i) a[i] = *(const s16x8*)&As[mw + (i << 4) + lr][ko];
#pragma unroll
      for (int j = 0; j < 2; ++j) bb[j] = *(const s16x8*)&Bs[nw + (j << 4) + lr][ko];
#pragma unroll
      for (int i = 0; i < 2; ++i)
#pragma unroll
        for (int j = 0; j < 2; ++j) acc[i][j] = mfma16(a[i], bb[j], acc[i][j]);
    }
    __syncthreads();
  }
#pragma unroll
  for (int i = 0; i < 2; ++i) {
    const int row = mw + (i << 4) + (lq << 2);
#pragma unroll
    for (int j = 0; j < 2; ++j) {
      const int col = nw + (j << 4) + lr;
#pragma unroll
      for (int r = 0; r < 2; ++r) {
        Y[(size_t)(m0 + row + 2 * r) * C_ + n0 + col] = f2bf(acc[i][j][2 * r] * sc);
        Y[(size_t)(m0 + row + 2 * r + 1) * C_ + n0 + col] =
            f2bf(acc[i][j][2 * r + 1] * sc);
      }
    }
  }
}

// ---------------- V = Wv @ X  -> [o][t] bf16, 64x64 tiles ----------------
__global__ __launch_bounds__(256) void gemm_v(const u16* __restrict__ xt,
                                              const float* __restrict__ wv,
                                              u16* __restrict__ vout) {
  const int b = blockIdx.z;
  const int n0 = blockIdx.x << 6;  // t
  const int m0 = blockIdx.y << 6;  // o
  const u16* __restrict__ Bg = xt + (size_t)b * (T_ * (size_t)C_);
  u16* __restrict__ Y = vout + (size_t)b * (C_ * (size_t)T_);
  __shared__ u16 As[64][72];
  __shared__ u16 Bs[64][72];
  const int tid = threadIdx.x;
  const int w = tid >> 6, lane = tid & 63, lr = lane & 15, lq = lane >> 4;
  const int mw = (w >> 1) << 5, nw = (w & 1) << 5;
  f32x4 acc[2][2] = {};
  for (int k0 = 0; k0 < C_; k0 += 64) {
#pragma unroll
    for (int it = 0; it < 2; ++it) {
      const int e = tid + (it << 8);
      const int r = e >> 3, c8 = e & 7;
      const float* wr = wv + (size_t)(m0 + r) * C_ + k0 + (c8 << 3);
      const float4 f0 = *(const float4*)wr;
      const float4 f1 = *(const float4*)(wr + 4);
      u16x8 o;
      o[0] = f2bf(f0.x); o[1] = f2bf(f0.y); o[2] = f2bf(f0.z); o[3] = f2bf(f0.w);
      o[4] = f2bf(f1.x); o[5] = f2bf(f1.y); o[6] = f2bf(f1.z); o[7] = f2bf(f1.w);
      *(u16x8*)&As[r][c8 << 3] = o;
      *(u16x8*)&Bs[r][c8 << 3] =
          *(const u16x8*)(Bg + (size_t)(n0 + r) * C_ + k0 + (c8 << 3));
    }
    __syncthreads();
#pragma unroll
    for (int kf = 0; kf < 2; ++kf) {
      const int ko = (kf << 5) + (lq << 3);
      s16x8 a[2], bb[2];
#pragma unroll
      for (int i = 0; i < 2; ++i) a[i] = *(const s16x8*)&As[mw + (i << 4) + lr][ko];
#pragma unroll
      for (int j = 0; j < 2; ++j) bb[j] = *(const s16x8*)&Bs[nw + (j << 4) + lr][ko];
#pragma unroll
      for (int i = 0; i < 2; ++i)
#pragma unroll
        for (int j = 0; j < 2; ++j) acc[i][j] = mfma16(a[i], bb[j], acc[i][j]);
    }
    __syncthreads();
  }
#pragma unroll
  for (int i = 0; i < 2; ++i) {
    const int row = mw + (i << 4) + (lq << 2);
#pragma unroll
    for (int j = 0; j < 2; ++j) {
      const int col = nw + (j << 4) + lr;
#pragma unroll
      for (int r = 0; r < 4; ++r)
        Y[(size_t)(m0 + row + r) * T_ + n0 + col] = f2bf(acc[i][j][r]);
    }
  }
}

// ---------------- vsum[b][g][d] = sum_t V ----------------
__global__ __launch_bounds__(256) void vsum_k(const u16* __restrict__ v,
                                              float* __restrict__ vsum) {
  const int bg = blockIdx.x;  // b*8+g
  const int tid = threadIdx.x;
  const int d = tid >> 2, part = tid & 3;
  const u16* __restrict__ Vr =
      v + ((size_t)(bg >> 3) * C_ + ((bg & 7) << 6) + d) * T_ + (part << 8);
  float s = 0.f;
  for (int t = 0; t < 256; t += 8) {
    const u16x8 x = *(const u16x8*)(Vr + t);
#pragma unroll
    for (int j = 0; j < 8; ++j) s += b2f(x[j]);
  }
  s += __shfl_down(s, 2, 64);
  s += __shfl_down(s, 1, 64);
  if (part == 0) vsum[(bg << 6) + d] = s;
}

// ---------------- fused attention: QK^T -> mix -> exp -> PV -> /l ----------
// block (q16, gh 0..3, b): 16 q, 2 groups, full t sweep. G=2 keeps per-wave
// state ~100 regs -> __launch_bounds__(256,4): 4 blocks/CU, 16 waves/CU.
// Permuted K rows make each lane's t-slots contiguous (tb+quad*8+0..7) so
// V B-frags are single u16x8 loads.
__global__ __launch_bounds__(256, 4) void fused_attn(
    const u16* __restrict__ Qt, const u16* __restrict__ Kt,
    const u16* __restrict__ V, const float* __restrict__ wh,
    u16* __restrict__ O, float* __restrict__ pssq) {
  const int q16 = blockIdx.x;
  const int gh = blockIdx.y;  // pair index 0..3
  const int b = blockIdx.z;
  const int tid = threadIdx.x;
  const int w = tid >> 6, lane = tid & 63;
  const int lr = lane & 15, quad = lane >> 4;
  const int q0 = q16 << 4;

  const u16* __restrict__ Kb = Kt + (size_t)b * T_ * C_;
  const u16* __restrict__ Vb = V + ((size_t)b * C_ + (gh << 7)) * T_;

  __shared__ u16 Qs[16][520];
  __shared__ float Ored[16][136];
  __shared__ float lredA[4][2][16];
  __shared__ float lredB[4][2][16];
  __shared__ float lT[2][16];

  {
    const u16* Qb = Qt + ((size_t)b * T_ + q0) * C_;
    for (int i = tid; i < 1024; i += 256) {
      const int r = i >> 6, c8 = i & 63;
      *(u16x8*)&Qs[r][c8 << 3] = *(const u16x8*)(Qb + (size_t)r * C_ + (c8 << 3));
    }
  }
  __syncthreads();

  f32x4 Oacc[2][4] = {};
  float lsum[2] = {}, l2sum[2] = {};
  const int tp = ((lr >> 2) << 3) + (lr & 3);  // permuted t row (a0); a1 = +4

#pragma unroll 1
  for (int sl = 0; sl < 8; ++sl) {
    const int tb = (sl << 7) + (w << 5);
    f32x4 m[2][2] = {};
#pragma unroll 2
    for (int h = 0; h < 8; ++h) {
      f32x4 a0 = {0.f, 0.f, 0.f, 0.f}, a1 = {0.f, 0.f, 0.f, 0.f};
#pragma unroll
      for (int kf = 0; kf < 2; ++kf) {
        const int co = (h << 6) + (kf << 5) + (quad << 3);
        const s16x8 qfr = *(const s16x8*)&Qs[lr][co];
        const s16x8 k0 = *(const s16x8*)(Kb + (size_t)(tb + tp) * C_ + co);
        const s16x8 k1 = *(const s16x8*)(Kb + (size_t)(tb + tp + 4) * C_ + co);
        a0 = mfma16(k0, qfr, a0);
        a1 = mfma16(k1, qfr, a1);
      }
#pragma unroll
      for (int g = 0; g < 2; ++g) {
        const float wgh = wh[(((gh << 1) + g) << 3) + h];  // uniform -> SGPR
        m[g][0] += a0 * wgh;
        m[g][1] += a1 * wgh;
      }
    }
    // lane's t slots: a0 -> tb+quad*8+{0..3}, a1 -> tb+quad*8+{4..7}
#pragma unroll
    for (int g = 0; g < 2; ++g) {
      f32x4 e0, e1;
#pragma unroll
      for (int k = 0; k < 4; ++k) {
        e0[k] = __expf(m[g][0][k]);
        e1[k] = __expf(m[g][1][k]);
      }
      lsum[g] += e0[0] + e0[1] + e0[2] + e0[3] + e1[0] + e1[1] + e1[2] + e1[3];
      l2sum[g] += e0[0] * e0[0] + e0[1] * e0[1] + e0[2] * e0[2] + e0[3] * e0[3] +
                  e1[0] * e1[0] + e1[1] * e1[1] + e1[2] * e1[2] + e1[3] * e1[3];
      s16x8 pa;
#pragma unroll
      for (int k = 0; k < 4; ++k) {
        pa[k] = (short)f2bf(e0[k]);
        pa[k + 4] = (short)f2bf(e1[k]);
      }
#pragma unroll
      for (int dt = 0; dt < 4; ++dt) {
        const s16x8 vb = *(const s16x8*)(
            Vb + (size_t)((g << 6) + (dt << 4) + lr) * T_ + tb + (quad << 3));
        Oacc[g][dt] = mfma16(pa, vb, Oacc[g][dt]);
      }
    }
  }

  // reduce l across quads (lane's q = lane&15)
#pragma unroll
  for (int g = 0; g < 2; ++g) {
    lsum[g] += __shfl_xor(lsum[g], 16, 64);
    lsum[g] += __shfl_xor(lsum[g], 32, 64);
    l2sum[g] += __shfl_xor(l2sum[g], 16, 64);
    l2sum[g] += __shfl_xor(l2sum[g], 32, 64);
  }
  // phased cross-wave O reduction in LDS
#pragma unroll 1
  for (int r = 0; r < 4; ++r) {
    if (w == r) {
#pragma unroll
      for (int g = 0; g < 2; ++g)
#pragma unroll
        for (int dt = 0; dt < 4; ++dt)
#pragma unroll
          for (int k = 0; k < 4; ++k) {
            const int q = (quad << 2) + k;
            const int c = (g << 6) + (dt << 4) + lr;
            if (r == 0)
              Ored[q][c] = Oacc[g][dt][k];
            else
              Ored[q][c] += Oacc[g][dt][k];
          }
    }
    __syncthreads();
  }
  if (lane < 16) {
#pragma unroll
    for (int g = 0; g < 2; ++g) {
      lredA[w][g][lane] = lsum[g];
      lredB[w][g][lane] = l2sum[g];
    }
  }
  __syncthreads();
  if (tid < 32) {
    const int g = tid >> 4, qq = tid & 15;
    const float l = lredA[0][g][qq] + lredA[1][g][qq] + lredA[2][g][qq] +
                    lredA[3][g][qq];
    const float l2v = lredB[0][g][qq] + lredB[1][g][qq] + lredB[2][g][qq] +
                      lredB[3][g][qq];
    lT[g][qq] = 1.f / l;
    float v = l2v / (l * l);
    v += __shfl_xor(v, 1, 64);
    v += __shfl_xor(v, 2, 64);
    v += __shfl_xor(v, 4, 64);
    v += __shfl_xor(v, 8, 64);
    if (qq == 0) pssq[(((b << 3) + (gh << 1) + g) << 6) + q16] = v;
  }
  __syncthreads();
  // write O[b][gh*2+g][q0+q][d] = Ored/l  (pre-affine): 16q x 128c
  for (int i = tid; i < 512; i += 256) {
    const int q = i >> 5, c4 = (i & 31) << 2;
    const int g = c4 >> 6, d = c4 & 63;
    const float inv = lT[g][q];
    u16x4 o;
#pragma unroll
    for (int j = 0; j < 4; ++j) o[j] = f2bf(Ored[q][c4 + j] * inv);
    *(u16x4*)(O + ((size_t)(((b << 3) + (gh << 1) + g) * T_ + q0 + q) << 6) + d) = o;
  }
}

// ---------------- stats: alpha/beta' per (b,g) ----------------
__global__ __launch_bounds__(64) void reduce_stats(
    const float* __restrict__ pssq, const float* __restrict__ gamma,
    const float* __restrict__ beta, float* __restrict__ ab) {
  const int bg = blockIdx.x;  // b*8+g
  const int g = bg & 7;
  const int tid = threadIdx.x;
  float s = pssq[(bg << 6) + tid];
#pragma unroll
  for (int off = 32; off; off >>= 1) s += __shfl_xor(s, off, 64);
  if (tid == 0) {
    const float mean = 0.0009765625f;
    const float var = s * (1.f / 1048576.f) - mean * mean;
    const float al = gamma[g] * rsqrtf(var + EPS_);
    ab[bg * 2] = al;
    ab[bg * 2 + 1] = beta[g] - al * mean;
  }
}

// -------- bias2[b][g][o] = bp[o] + bt2[b,g] * sum_d vsum[b,g,d]*wsum[o][d]
__global__ __launch_bounds__(256) void bias2_k(const float* __restrict__ wp,
                                               const float* __restrict__ bp,
                                               const float* __restrict__ ab,
                                               const float* __restrict__ vsum,
                                               float* __restrict__ bias2) {
  const int idx = (blockIdx.x << 8) + threadIdx.x;  // 16384 = B*8*512
  const int b = idx >> 12, g = (idx >> 9) & 7, o = idx & 511;
  const float bt2 = ab[(((b << 3) + g) << 1) + 1];
  const float* wr = wp + (size_t)o * C_;
  const float* vs = vsum + (((b << 3) + g) << 6);
  float acc = 0.f;
#pragma unroll
  for (int d = 0; d < 64; d += 4) {
    const float4 vv4 = *(const float4*)(vs + d);
    float4 ws4 = {0.f, 0.f, 0.f, 0.f};
#pragma unroll
    for (int j = 0; j < 8; ++j) {
      const float4 wv4 = *(const float4*)(wr + (j << 6) + d);
      ws4.x += wv4.x; ws4.y += wv4.y; ws4.z += wv4.z; ws4.w += wv4.w;
    }
    acc += ws4.x * vv4.x + ws4.y * vv4.y + ws4.z * vv4.z + ws4.w * vv4.w;
  }
  bias2[(((b << 3) + g) << 9) + o] = bp[o] + bt2 * acc;
}

// ------- y = al[b,g(t)]*(Mnorm @ Wp^T) + bias2[b][g(t)][o], 64x64 tiles ----
// g(t) = t>>7 = blockIdx.x>>1 (64-wide aligned t tiles) -> uniform per block.
__global__ __launch_bounds__(256) void gemm_proj(const u16* __restrict__ O,
                                                 const float* __restrict__ wp,
                                                 const float* __restrict__ ab,
                                                 const float* __restrict__ bias2,
                                                 float* __restrict__ y) {
  const int b = blockIdx.z;
  const int m0 = blockIdx.y << 6;  // o
  const int n0 = blockIdx.x << 6;  // t
  const int gidx = blockIdx.x >> 1;
  const u16* __restrict__ Ob = O + (size_t)b * (8 * T_ * 64);
  __shared__ u16 As[64][72];
  __shared__ u16 Bs[64][72];
  const int tid = threadIdx.x;
  const int w = tid >> 6, lane = tid & 63, lr = lane & 15, lq = lane >> 4;
  const int mw = (w >> 1) << 5, nw = (w & 1) << 5;
  f32x4 acc[2][2] = {};
  for (int k0 = 0; k0 < C_; k0 += 64) {
#pragma unroll
    for (int it = 0; it < 2; ++it) {
      const int e = tid + (it << 8);
      const int r = e >> 3, c8 = e & 7;
      const float* wr = wp + (size_t)(m0 + r) * C_ + k0 + (c8 << 3);
      const float4 f0 = *(const float4*)wr;
      const float4 f1 = *(const float4*)(wr + 4);
      u16x8 o;
      o[0] = f2bf(f0.x); o[1] = f2bf(f0.y); o[2] = f2bf(f0.z); o[3] = f2bf(f0.w);
      o[4] = f2bf(f1.x); o[5] = f2bf(f1.y); o[6] = f2bf(f1.z); o[7] = f2bf(f1.w);
      *(u16x8*)&As[r][c8 << 3] = o;
      const int t = n0 + r;
      const int c = k0 + (c8 << 3);
      *(u16x8*)&Bs[r][c8 << 3] =
          *(const u16x8*)(Ob + (size_t)(t >> 7) * (T_ * 64) +
                          (size_t)(((t & 127) << 3) + (c >> 6)) * 64 + (c & 63));
    }
    __syncthreads();
#pragma unroll
    for (int kf = 0; kf < 2; ++kf) {
      const int ko = (kf << 5) + (lq << 3);
      s16x8 a[2], bb[2];
#pragma unroll
      for (int i = 0; i < 2; ++i) a[i] = *(const s16x8*)&As[mw + (i << 4) + lr][ko];
#pragma unroll
      for (int j = 0; j < 2; ++j) bb[j] = *(const s16x8*)&Bs[nw + (j << 4) + lr][ko];
#pragma unroll
      for (int i = 0; i < 2; ++i)
#pragma unroll
        for (int j = 0; j < 2; ++j) acc[i][j] = mfma16(a[i], bb[j], acc[i][j]);
    }
    __syncthreads();
  }
  const float al = ab[(((b << 3) + gidx) << 1)];
  const float* __restrict__ b2 = bias2 + (((b << 3) + gidx) << 9);
#pragma unroll
  for (int i = 0; i < 2; ++i) {
    const int row = mw + (i << 4) + (lq << 2);
#pragma unroll
    for (int j = 0; j < 2; ++j) {
      const int col = nw + (j << 4) + lr;
#pragma unroll
      for (int r = 0; r < 4; ++r)
        y[(size_t)b * (C_ * (size_t)T_) + (size_t)(m0 + row + r) * T_ + n0 + col] =
            acc[i][j][r] * al + b2[m0 + row + r];
    }
  }
}

extern "C" void kernel_launch(void* const* d_in, const int* in_sizes, int n_in,
                              void* d_out, int out_size, void* d_ws,
                              size_t ws_size, hipStream_t stream) {
  const float* x = (const float*)d_in[0];
  const float* wq = (const float*)d_in[1];
  const float* wk = (const float*)d_in[2];
  const float* wv = (const float*)d_in[3];
  const float* wh = (const float*)d_in[4];
  const float* gm = (const float*)d_in[5];
  const float* bt = (const float*)d_in[6];
  const float* wp = (const float*)d_in[7];
  const float* bp = (const float*)d_in[8];
  float* y = (float*)d_out;
  char* wsb = (char*)d_ws;

  u16* Qt = (u16*)(wsb + QT_OFF);
  u16* Kt = (u16*)(wsb + KT_OFF);
  u16* V = (u16*)(wsb + V_OFF);
  u16* Xt = (u16*)(wsb + XT_OFF);
  u16* Og = (u16*)(wsb + O_OFF);
  float* pssq = (float*)(wsb + PSSQ_OFF);
  float* ab = (float*)(wsb + AB_OFF);
  float* vsum = (float*)(wsb + VSUM_OFF);
  float* bias2 = (float*)(wsb + BIAS2_OFF);

  transpose_x<<<dim3(16, 8, 4), 256, 0, stream>>>(x, Xt);
  gemm_qkt<<<dim3(16, 8, 8), 256, 0, stream>>>(Xt, wq, wk, Qt, Kt);
  gemm_v<<<dim3(16, 8, 4), 256, 0, stream>>>(Xt, wv, V);
  vsum_k<<<dim3(32), 256, 0, stream>>>(V, vsum);
  fused_attn<<<dim3(64, 4, 4), 256, 0, stream>>>(Qt, Kt, V, wh, Og, pssq);
  reduce_stats<<<dim3(32), 64, 0, stream>>>(pssq, gm, bt, ab);
  bias2_k<<<dim3(64), 256, 0, stream>>>(wp, bp, ab, vsum, bias2);
  gemm_proj<<<dim3(16, 8, 4), 256, 0, stream>>>(Og, wp, ab, bias2, y);
}

// Round 9
// 244.059 us; speedup vs baseline: 1.2382x; 1.1754x over previous
//
#include <hip/hip_runtime.h>
#include <hip/hip_bf16.h>

#define B_ 4
#define C_ 512
#define T_ 1024
#define SCALE_ 0.125f
#define EPS_ 1e-5f

typedef unsigned short u16;
typedef __attribute__((ext_vector_type(8))) unsigned short u16x8;
typedef __attribute__((ext_vector_type(4))) unsigned short u16x4;
typedef __attribute__((ext_vector_type(8))) short s16x8;
typedef __attribute__((ext_vector_type(4))) float f32x4;

// ws byte offsets (ws is 256 MiB)
#define QT_OFF    (0x0ull)         // bf16 Qt[B][T][C]   4 MB (Q pre-scaled by 1/8)
#define KT_OFF    (0x400000ull)    // bf16 Kt[B][T][C]   4 MB
#define V_OFF     (0x800000ull)    // bf16 V [B][C][T]   4 MB
#define XT_OFF    (0xC00000ull)    // bf16 Xt[B][T][C]   4 MB
#define O_OFF     (0x1000000ull)   // bf16 O[B][8][T][64] 4 MB (normalized, pre-affine)
#define AB_OFF    (0x1410000ull)   // fp32 ab[B][8][2]
#define VSUM_OFF  (0x1420000ull)   // fp32 vsum[B][8][64]
#define BIAS2_OFF (0x1430000ull)   // fp32 bias2[B][8][512]
#define P_OFF     (0x2000000ull)   // bf16 P[B*8][1024][1024] 64 MB (unnormalized exp)
#define LP_OFF    (0x6000000ull)   // fp32 lpart [B*8][1024][32] 4 MB
#define L2P_OFF   (0x6400000ull)   // fp32 l2part[B*8][1024][32] 4 MB
#define LINV_OFF  (0x6800000ull)   // fp32 linv[B*8][1024] 128 KB

static __device__ __forceinline__ u16 f2bf(float f) {
  unsigned u = __float_as_uint(f);
  unsigned r = (u + 0x7fff + ((u >> 16) & 1)) >> 16;  // RNE
  return (u16)r;
}
static __device__ __forceinline__ float b2f(u16 x) {
  return __uint_as_float(((unsigned)x) << 16);
}
static __device__ __forceinline__ f32x4 mfma16(s16x8 a, s16x8 b, f32x4 c) {
  return __builtin_amdgcn_mfma_f32_16x16x32_bf16(a, b, c, 0, 0, 0);
}

// ---------------- transpose x -> Xt[b][t][c] bf16 ----------------
__global__ __launch_bounds__(256) void transpose_x(const float* __restrict__ x,
                                                   u16* __restrict__ xt) {
  const int b = blockIdx.z;
  const int t0 = blockIdx.x << 6;
  const int c0 = blockIdx.y << 6;
  const float* __restrict__ X = x + (size_t)b * (C_ * (size_t)T_);
  u16* __restrict__ Xt = xt + (size_t)b * (T_ * (size_t)C_);
  __shared__ float Ts[64][65];
  const int tid = threadIdx.x;
#pragma unroll
  for (int i = 0; i < 4; ++i) {
    const int e = tid + (i << 8);
    const int r = e >> 4, c4 = e & 15;
    const float4 v = *(const float4*)(X + (size_t)(c0 + r) * T_ + t0 + (c4 << 2));
    Ts[r][(c4 << 2) + 0] = v.x; Ts[r][(c4 << 2) + 1] = v.y;
    Ts[r][(c4 << 2) + 2] = v.z; Ts[r][(c4 << 2) + 3] = v.w;
  }
  __syncthreads();
#pragma unroll
  for (int i = 0; i < 2; ++i) {
    const int e = tid + (i << 8);
    const int tt = e >> 3, c8 = e & 7;
    u16x8 o;
#pragma unroll
    for (int j = 0; j < 8; ++j) o[j] = f2bf(Ts[(c8 << 3) + j][tt]);
    *(u16x8*)(Xt + (size_t)(t0 + tt) * C_ + c0 + (c8 << 3)) = o;
  }
}

// ------- Qt/Kt = Xt @ W^T -> [t][o] bf16 (Q scaled by 1/8), 64x64 tiles -----
__global__ __launch_bounds__(256) void gemm_qkt(const u16* __restrict__ xt,
                                                const float* __restrict__ wq,
                                                const float* __restrict__ wk,
                                                u16* __restrict__ qto,
                                                u16* __restrict__ kto) {
  const int which = blockIdx.z >> 2;
  const int b = blockIdx.z & 3;
  const float* __restrict__ W = which ? wk : wq;
  u16* __restrict__ Y = (which ? kto : qto) + (size_t)b * (T_ * (size_t)C_);
  const u16* __restrict__ A = xt + (size_t)b * (T_ * (size_t)C_);
  const float sc = which ? 1.0f : SCALE_;
  const int m0 = blockIdx.x << 6;  // t
  const int n0 = blockIdx.y << 6;  // o
  __shared__ u16 As[64][72];
  __shared__ u16 Bs[64][72];
  const int tid = threadIdx.x;
  const int w = tid >> 6, lane = tid & 63, lr = lane & 15, lq = lane >> 4;
  const int mw = (w >> 1) << 5, nw = (w & 1) << 5;
  f32x4 acc[2][2] = {};
  for (int k0 = 0; k0 < C_; k0 += 64) {
#pragma unroll
    for (int it = 0; it < 2; ++it) {
      const int e = tid + (it << 8);
      const int r = e >> 3, c8 = e & 7;
      *(u16x8*)&As[r][c8 << 3] =
          *(const u16x8*)(A + (size_t)(m0 + r) * C_ + k0 + (c8 << 3));
      const float* wr = W + (size_t)(n0 + r) * C_ + k0 + (c8 << 3);
      const float4 f0 = *(const float4*)wr;
      const float4 f1 = *(const float4*)(wr + 4);
      u16x8 o;
      o[0] = f2bf(f0.x); o[1] = f2bf(f0.y); o[2] = f2bf(f0.z); o[3] = f2bf(f0.w);
      o[4] = f2bf(f1.x); o[5] = f2bf(f1.y); o[6] = f2bf(f1.z); o[7] = f2bf(f1.w);
      *(u16x8*)&Bs[r][c8 << 3] = o;
    }
    __syncthreads();
#pragma unroll
    for (int kf = 0; kf < 2; ++kf) {
      const int ko = (kf << 5) + (lq << 3);
      s16x8 a[2], bb[2];
#pragma unroll
      for (int i = 0; i < 2; ++i) a[i] = *(const s16x8*)&As[mw + (i << 4) + lr][ko];
#pragma unroll
      for (int j = 0; j < 2; ++j) bb[j] = *(const s16x8*)&Bs[nw + (j << 4) + lr][ko];
#pragma unroll
      for (int i = 0; i < 2; ++i)
#pragma unroll
        for (int j = 0; j < 2; ++j) acc[i][j] = mfma16(a[i], bb[j], acc[i][j]);
    }
    __syncthreads();
  }
#pragma unroll
  for (int i = 0; i < 2; ++i) {
    const int row = mw + (i << 4) + (lq << 2);
#pragma unroll
    for (int j = 0; j < 2; ++j) {
      const int col = nw + (j << 4) + lr;
#pragma unroll
      for (int r = 0; r < 4; ++r)
        Y[(size_t)(m0 + row + r) * C_ + n0 + col] = f2bf(acc[i][j][r] * sc);
    }
  }
}

// ---------------- V = Wv @ X  -> [o][t] bf16, 64x64 tiles ----------------
__global__ __launch_bounds__(256) void gemm_v(const u16* __restrict__ xt,
                                              const float* __restrict__ wv,
                                              u16* __restrict__ vout) {
  const int b = blockIdx.z;
  const int n0 = blockIdx.x << 6;  // t
  const int m0 = blockIdx.y << 6;  // o
  const u16* __restrict__ Bg = xt + (size_t)b * (T_ * (size_t)C_);
  u16* __restrict__ Y = vout + (size_t)b * (C_ * (size_t)T_);
  __shared__ u16 As[64][72];
  __shared__ u16 Bs[64][72];
  const int tid = threadIdx.x;
  const int w = tid >> 6, lane = tid & 63, lr = lane & 15, lq = lane >> 4;
  const int mw = (w >> 1) << 5, nw = (w & 1) << 5;
  f32x4 acc[2][2] = {};
  for (int k0 = 0; k0 < C_; k0 += 64) {
#pragma unroll
    for (int it = 0; it < 2; ++it) {
      const int e = tid + (it << 8);
      const int r = e >> 3, c8 = e & 7;
      const float* wr = wv + (size_t)(m0 + r) * C_ + k0 + (c8 << 3);
      const float4 f0 = *(const float4*)wr;
      const float4 f1 = *(const float4*)(wr + 4);
      u16x8 o;
      o[0] = f2bf(f0.x); o[1] = f2bf(f0.y); o[2] = f2bf(f0.z); o[3] = f2bf(f0.w);
      o[4] = f2bf(f1.x); o[5] = f2bf(f1.y); o[6] = f2bf(f1.z); o[7] = f2bf(f1.w);
      *(u16x8*)&As[r][c8 << 3] = o;
      *(u16x8*)&Bs[r][c8 << 3] =
          *(const u16x8*)(Bg + (size_t)(n0 + r) * C_ + k0 + (c8 << 3));
    }
    __syncthreads();
#pragma unroll
    for (int kf = 0; kf < 2; ++kf) {
      const int ko = (kf << 5) + (lq << 3);
      s16x8 a[2], bb[2];
#pragma unroll
      for (int i = 0; i < 2; ++i) a[i] = *(const s16x8*)&As[mw + (i << 4) + lr][ko];
#pragma unroll
      for (int j = 0; j < 2; ++j) bb[j] = *(const s16x8*)&Bs[nw + (j << 4) + lr][ko];
#pragma unroll
      for (int i = 0; i < 2; ++i)
#pragma unroll
        for (int j = 0; j < 2; ++j) acc[i][j] = mfma16(a[i], bb[j], acc[i][j]);
    }
    __syncthreads();
  }
#pragma unroll
  for (int i = 0; i < 2; ++i) {
    const int row = mw + (i << 4) + (lq << 2);
#pragma unroll
    for (int j = 0; j < 2; ++j) {
      const int col = nw + (j << 4) + lr;
#pragma unroll
      for (int r = 0; r < 4; ++r)
        Y[(size_t)(m0 + row + r) * T_ + n0 + col] = f2bf(acc[i][j][r]);
    }
  }
}

// ---------------- vsum[b][g][d] = sum_t V ----------------
__global__ __launch_bounds__(256) void vsum_k(const u16* __restrict__ v,
                                              float* __restrict__ vsum) {
  const int bg = blockIdx.x;  // b*8+g
  const int tid = threadIdx.x;
  const int d = tid >> 2, part = tid & 3;
  const u16* __restrict__ Vr =
      v + ((size_t)(bg >> 3) * C_ + ((bg & 7) << 6) + d) * T_ + (part << 8);
  float s = 0.f;
  for (int t = 0; t < 256; t += 8) {
    const u16x8 x = *(const u16x8*)(Vr + t);
#pragma unroll
    for (int j = 0; j < 8; ++j) s += b2f(x[j]);
  }
  s += __shfl_down(s, 2, 64);
  s += __shfl_down(s, 1, 64);
  if (part == 0) vsum[(bg << 6) + d] = s;
}

// ---- pass 1: S = Q·K^T (all 8 h), head-mix, exp (no max), P bf16 + l/l2 ----
// block = 32q x 32t x one batch; wave w = quadrant (qh=w>>1, th=w&1).
// QK computed ONCE per (q,t); tiny per-wave state (S[8]=32 regs) -> high TLP.
__global__ __launch_bounds__(256, 4) void qk_mix(const u16* __restrict__ Qt,
                                                 const u16* __restrict__ Kt,
                                                 const float* __restrict__ wh,
                                                 u16* __restrict__ P,
                                                 float* __restrict__ lpart,
                                                 float* __restrict__ l2part) {
  const int qb = blockIdx.x;  // q /32
  const int tb = blockIdx.y;  // t /32
  const int b = blockIdx.z;
  const int tid = threadIdx.x;
  const int w = tid >> 6, lane = tid & 63;
  const int lr = lane & 15, quad = lane >> 4;
  const int qh = w >> 1, th = w & 1;
  const int q0 = qb << 5, t0 = tb << 5;

  const u16* __restrict__ Qrow =
      Qt + ((size_t)b * T_ + q0 + (qh << 4) + lr) * C_ + (quad << 3);
  const u16* __restrict__ Krow =
      Kt + ((size_t)b * T_ + t0 + (th << 4) + lr) * C_ + (quad << 3);

  __shared__ float ldsL[4][8][16];
  __shared__ float ldsL2[4][8][16];

  f32x4 S[8] = {};
#pragma unroll 4
  for (int h = 0; h < 8; ++h) {
#pragma unroll
    for (int kf = 0; kf < 2; ++kf) {
      const int co = (h << 6) + (kf << 5);
      const s16x8 a = *(const s16x8*)(Qrow + co);
      const s16x8 bb = *(const s16x8*)(Krow + co);
      S[h] = mfma16(a, bb, S[h]);
    }
  }
  // C layout: row q = qh*16 + quad*4 + k, col t = th*16 + lr
  const int qloc = q0 + (qh << 4) + (quad << 2);
  const int tglob = t0 + (th << 4) + lr;
#pragma unroll
  for (int g = 0; g < 8; ++g) {
    f32x4 m = S[0] * wh[(g << 3)];
#pragma unroll
    for (int h = 1; h < 8; ++h) m += S[h] * wh[(g << 3) + h];  // wh uniform->SGPR
    f32x4 e;
#pragma unroll
    for (int k = 0; k < 4; ++k) e[k] = __expf(m[k]);
    // P store (4 q rows x 1 t col per lane)
    u16* Pp = P + (((size_t)((b << 3) + g) << 10) + qloc) * 1024 + tglob;
#pragma unroll
    for (int k = 0; k < 4; ++k) Pp[(size_t)k << 10] = f2bf(e[k]);
    // row sums over t: butterfly over lr bits (lane bits 0..3)
    f32x4 l = e, l2 = e * e;
#pragma unroll
    for (int bit = 1; bit < 16; bit <<= 1) {
#pragma unroll
      for (int k = 0; k < 4; ++k) {
        l[k] += __shfl_xor(l[k], bit, 64);
        l2[k] += __shfl_xor(l2[k], bit, 64);
      }
    }
    if (lr == 0) {
      *(f32x4*)&ldsL[w][g][quad << 2] = l;
      *(f32x4*)&ldsL2[w][g][quad << 2] = l2;
    }
  }
  __syncthreads();
  // 256 threads = 8 g x 32 q: combine the two t-halves, write partials
  {
    const int g = tid >> 5, qq = tid & 31;
    const int wa = (qq < 16) ? 0 : 2;
    const int qi = qq & 15;
    const float lv = ldsL[wa][g][qi] + ldsL[wa + 1][g][qi];
    const float l2v = ldsL2[wa][g][qi] + ldsL2[wa + 1][g][qi];
    const size_t idx = ((((size_t)(b << 3) + g) << 10) + q0 + qq) * 32 + tb;
    lpart[idx] = lv;
    l2part[idx] = l2v;
  }
}

// ---- reduce l partials: linv[bg][q], and alpha/beta' per (b,g) -> ab ----
__global__ __launch_bounds__(256) void reduce_l(const float* __restrict__ lpart,
                                                const float* __restrict__ l2part,
                                                const float* __restrict__ gamma,
                                                const float* __restrict__ beta,
                                                float* __restrict__ linv,
                                                float* __restrict__ ab) {
  const int bg = blockIdx.x;
  const int g = bg & 7;
  const int tid = threadIdx.x;
  float ssq = 0.f;
#pragma unroll
  for (int k = 0; k < 4; ++k) {
    const int q = (tid << 2) + k;
    const float* lp = lpart + (((size_t)bg << 10) + q) * 32;
    const float* l2p = l2part + (((size_t)bg << 10) + q) * 32;
    float l = 0.f, l2 = 0.f;
#pragma unroll
    for (int j = 0; j < 32; j += 4) {
      const f32x4 a = *(const f32x4*)(lp + j);
      const f32x4 c = *(const f32x4*)(l2p + j);
      l += a[0] + a[1] + a[2] + a[3];
      l2 += c[0] + c[1] + c[2] + c[3];
    }
    linv[((size_t)bg << 10) + q] = 1.f / l;
    ssq += l2 / (l * l);
  }
#pragma unroll
  for (int off = 32; off; off >>= 1) ssq += __shfl_xor(ssq, off, 64);
  __shared__ float red[4];
  if ((tid & 63) == 0) red[tid >> 6] = ssq;
  __syncthreads();
  if (tid == 0) {
    const float s = red[0] + red[1] + red[2] + red[3];
    const float mean = 0.0009765625f;
    const float var = s * (1.f / 1048576.f) - mean * mean;
    const float al = gamma[g] * rsqrtf(var + EPS_);
    ab[bg * 2] = al;
    ab[bg * 2 + 1] = beta[g] - al * mean;
  }
}

// ---- pass 2: O[bg][q][d] = (P[q][:] @ V[d][:]^T) * linv[q]  (64q x 64d) ----
__global__ __launch_bounds__(256) void gemm_pv(const u16* __restrict__ P,
                                               const u16* __restrict__ v,
                                               const float* __restrict__ linv,
                                               u16* __restrict__ O) {
  const int qt0 = blockIdx.x << 6;
  const int bg = blockIdx.y;
  const u16* __restrict__ A = P + (((size_t)bg << 10) + qt0) * 1024;
  const u16* __restrict__ Vg =
      v + ((size_t)(bg >> 3) * C_ + ((bg & 7) << 6)) * 1024;
  __shared__ u16 Ps[64][40];
  __shared__ u16 Vs[64][40];
  __shared__ float lT[64];
  const int tid = threadIdx.x;
  const int w = tid >> 6, lane = tid & 63, lr = lane & 15, quad = lane >> 4;
  if (tid < 64) lT[tid] = linv[((size_t)bg << 10) + qt0 + tid];
  f32x4 acc[4] = {};
  const int r = tid >> 2, c4 = tid & 3;
#pragma unroll 1
  for (int k0 = 0; k0 < 1024; k0 += 32) {
    __syncthreads();
    *(u16x8*)&Ps[r][c4 << 3] =
        *(const u16x8*)(A + (size_t)r * 1024 + k0 + (c4 << 3));
    *(u16x8*)&Vs[r][c4 << 3] =
        *(const u16x8*)(Vg + (size_t)r * 1024 + k0 + (c4 << 3));
    __syncthreads();
    const s16x8 a = *(const s16x8*)&Ps[(w << 4) + lr][quad << 3];
#pragma unroll
    for (int j = 0; j < 4; ++j) {
      const s16x8 bb = *(const s16x8*)&Vs[(j << 4) + lr][quad << 3];
      acc[j] = mfma16(a, bb, acc[j]);
    }
  }
#pragma unroll
  for (int j = 0; j < 4; ++j) {
    const int d = (j << 4) + lr;
#pragma unroll
    for (int rr = 0; rr < 4; ++rr) {
      const int q = (w << 4) + (quad << 2) + rr;
      O[(((size_t)bg << 10) + qt0 + q) * 64 + d] = f2bf(acc[j][rr] * lT[q]);
    }
  }
}

// -------- bias2[b][g][o] = bp[o] + bt2[b,g] * sum_d vsum[b,g,d]*wsum[o][d]
__global__ __launch_bounds__(256) void bias2_k(const float* __restrict__ wp,
                                               const float* __restrict__ bp,
                                               const float* __restrict__ ab,
                                               const float* __restrict__ vsum,
                                               float* __restrict__ bias2) {
  const int idx = (blockIdx.x << 8) + threadIdx.x;  // 16384 = B*8*512
  const int b = idx >> 12, g = (idx >> 9) & 7, o = idx & 511;
  const float bt2 = ab[(((b << 3) + g) << 1) + 1];
  const float* wr = wp + (size_t)o * C_;
  const float* vs = vsum + (((b << 3) + g) << 6);
  float acc = 0.f;
#pragma unroll
  for (int d = 0; d < 64; d += 4) {
    const float4 vv4 = *(const float4*)(vs + d);
    float4 ws4 = {0.f, 0.f, 0.f, 0.f};
#pragma unroll
    for (int j = 0; j < 8; ++j) {
      const float4 wv4 = *(const float4*)(wr + (j << 6) + d);
      ws4.x += wv4.x; ws4.y += wv4.y; ws4.z += wv4.z; ws4.w += wv4.w;
    }
    acc += ws4.x * vv4.x + ws4.y * vv4.y + ws4.z * vv4.z + ws4.w * vv4.w;
  }
  bias2[(((b << 3) + g) << 9) + o] = bp[o] + bt2 * acc;
}

// ------- y = al[b,g(t)]*(Mnorm @ Wp^T) + bias2[b][g(t)][o], 64x64 tiles ----
__global__ __launch_bounds__(256) void gemm_proj(const u16* __restrict__ O,
                                                 const float* __restrict__ wp,
                                                 const float* __restrict__ ab,
                                                 const float* __restrict__ bias2,
                                                 float* __restrict__ y) {
  const int b = blockIdx.z;
  const int m0 = blockIdx.y << 6;  // o
  const int n0 = blockIdx.x << 6;  // t
  const int gidx = blockIdx.x >> 1;
  const u16* __restrict__ Ob = O + (size_t)b * (8 * T_ * 64);
  __shared__ u16 As[64][72];
  __shared__ u16 Bs[64][72];
  const int tid = threadIdx.x;
  const int w = tid >> 6, lane = tid & 63, lr = lane & 15, lq = lane >> 4;
  const int mw = (w >> 1) << 5, nw = (w & 1) << 5;
  f32x4 acc[2][2] = {};
  for (int k0 = 0; k0 < C_; k0 += 64) {
#pragma unroll
    for (int it = 0; it < 2; ++it) {
      const int e = tid + (it << 8);
      const int r = e >> 3, c8 = e & 7;
      const float* wr = wp + (size_t)(m0 + r) * C_ + k0 + (c8 << 3);
      const float4 f0 = *(const float4*)wr;
      const float4 f1 = *(const float4*)(wr + 4);
      u16x8 o;
      o[0] = f2bf(f0.x); o[1] = f2bf(f0.y); o[2] = f2bf(f0.z); o[3] = f2bf(f0.w);
      o[4] = f2bf(f1.x); o[5] = f2bf(f1.y); o[6] = f2bf(f1.z); o[7] = f2bf(f1.w);
      *(u16x8*)&As[r][c8 << 3] = o;
      const int t = n0 + r;
      const int c = k0 + (c8 << 3);
      *(u16x8*)&Bs[r][c8 << 3] =
          *(const u16x8*)(Ob + (size_t)(t >> 7) * (T_ * 64) +
                          (size_t)(((t & 127) << 3) + (c >> 6)) * 64 + (c & 63));
    }
    __syncthreads();
#pragma unroll
    for (int kf = 0; kf < 2; ++kf) {
      const int ko = (kf << 5) + (lq << 3);
      s16x8 a[2], bb[2];
#pragma unroll
      for (int i = 0; i < 2; ++i) a[i] = *(const s16x8*)&As[mw + (i << 4) + lr][ko];
#pragma unroll
      for (int j = 0; j < 2; ++j) bb[j] = *(const s16x8*)&Bs[nw + (j << 4) + lr][ko];
#pragma unroll
      for (int i = 0; i < 2; ++i)
#pragma unroll
        for (int j = 0; j < 2; ++j) acc[i][j] = mfma16(a[i], bb[j], acc[i][j]);
    }
    __syncthreads();
  }
  const float al = ab[(((b << 3) + gidx) << 1)];
  const float* __restrict__ b2 = bias2 + (((b << 3) + gidx) << 9);
#pragma unroll
  for (int i = 0; i < 2; ++i) {
    const int row = mw + (i << 4) + (lq << 2);
#pragma unroll
    for (int j = 0; j < 2; ++j) {
      const int col = nw + (j << 4) + lr;
#pragma unroll
      for (int r = 0; r < 4; ++r)
        y[(size_t)b * (C_ * (size_t)T_) + (size_t)(m0 + row + r) * T_ + n0 + col] =
            acc[i][j][r] * al + b2[m0 + row + r];
    }
  }
}

extern "C" void kernel_launch(void* const* d_in, const int* in_sizes, int n_in,
                              void* d_out, int out_size, void* d_ws,
                              size_t ws_size, hipStream_t stream) {
  const float* x = (const float*)d_in[0];
  const float* wq = (const float*)d_in[1];
  const float* wk = (const float*)d_in[2];
  const float* wv = (const float*)d_in[3];
  const float* wh = (const float*)d_in[4];
  const float* gm = (const float*)d_in[5];
  const float* bt = (const float*)d_in[6];
  const float* wp = (const float*)d_in[7];
  const float* bp = (const float*)d_in[8];
  float* y = (float*)d_out;
  char* wsb = (char*)d_ws;

  u16* Qt = (u16*)(wsb + QT_OFF);
  u16* Kt = (u16*)(wsb + KT_OFF);
  u16* V = (u16*)(wsb + V_OFF);
  u16* Xt = (u16*)(wsb + XT_OFF);
  u16* Og = (u16*)(wsb + O_OFF);
  float* ab = (float*)(wsb + AB_OFF);
  float* vsum = (float*)(wsb + VSUM_OFF);
  float* bias2 = (float*)(wsb + BIAS2_OFF);
  u16* P = (u16*)(wsb + P_OFF);
  float* lpart = (float*)(wsb + LP_OFF);
  float* l2part = (float*)(wsb + L2P_OFF);
  float* linv = (float*)(wsb + LINV_OFF);

  transpose_x<<<dim3(16, 8, 4), 256, 0, stream>>>(x, Xt);
  gemm_qkt<<<dim3(16, 8, 8), 256, 0, stream>>>(Xt, wq, wk, Qt, Kt);
  gemm_v<<<dim3(16, 8, 4), 256, 0, stream>>>(Xt, wv, V);
  vsum_k<<<dim3(32), 256, 0, stream>>>(V, vsum);
  qk_mix<<<dim3(32, 32, 4), 256, 0, stream>>>(Qt, Kt, wh, P, lpart, l2part);
  reduce_l<<<dim3(32), 256, 0, stream>>>(lpart, l2part, gm, bt, linv, ab);
  gemm_pv<<<dim3(16, 32), 256, 0, stream>>>(P, V, linv, Og);
  bias2_k<<<dim3(64), 256, 0, stream>>>(wp, bp, ab, vsum, bias2);
  gemm_proj<<<dim3(16, 8, 4), 256, 0, stream>>>(Og, wp, ab, bias2, y);
}

// Round 10
// 208.885 us; speedup vs baseline: 1.4467x; 1.1684x over previous
//
#include <hip/hip_runtime.h>
#include <hip/hip_bf16.h>

#define B_ 4
#define C_ 512
#define T_ 1024
#define SCALE_ 0.125f
#define EPS_ 1e-5f

typedef unsigned short u16;
typedef __attribute__((ext_vector_type(8))) unsigned short u16x8;
typedef __attribute__((ext_vector_type(4))) unsigned short u16x4;
typedef __attribute__((ext_vector_type(8))) short s16x8;
typedef __attribute__((ext_vector_type(4))) float f32x4;

// ws byte offsets (ws is 256 MiB)
#define QT_OFF    (0x0ull)         // bf16 Qt[B][T][C]   4 MB (Q pre-scaled by 1/8)
#define KT_OFF    (0x400000ull)    // bf16 Kt[B][T][C]   4 MB
#define V_OFF     (0x800000ull)    // bf16 V [B][C][T]   4 MB
#define XT_OFF    (0xC00000ull)    // bf16 Xt[B][T][C]   4 MB
#define O_OFF     (0x1000000ull)   // bf16 O[B][8][T][64] 4 MB (normalized, pre-affine)
#define AB_OFF    (0x1410000ull)   // fp32 ab[B][8][2]
#define VSUM_OFF  (0x1420000ull)   // fp32 vsum[B][8][64]
#define BIAS2_OFF (0x1430000ull)   // fp32 bias2[B][8][512]
#define P_OFF     (0x2000000ull)   // bf16 P[B*8][1024][1024] 64 MB (unnormalized exp)
#define LP_OFF    (0x6000000ull)   // fp32 lpart [B*8][1024][32] 4 MB
#define L2P_OFF   (0x6400000ull)   // fp32 l2part[B*8][1024][32] 4 MB
#define LINV_OFF  (0x6800000ull)   // fp32 linv[B*8][1024] 128 KB

static __device__ __forceinline__ u16 f2bf(float f) {
  unsigned u = __float_as_uint(f);
  unsigned r = (u + 0x7fff + ((u >> 16) & 1)) >> 16;  // RNE
  return (u16)r;
}
static __device__ __forceinline__ float b2f(u16 x) {
  return __uint_as_float(((unsigned)x) << 16);
}
static __device__ __forceinline__ f32x4 mfma16(s16x8 a, s16x8 b, f32x4 c) {
  return __builtin_amdgcn_mfma_f32_16x16x32_bf16(a, b, c, 0, 0, 0);
}

// ---------------- transpose x -> Xt[b][t][c] bf16 ----------------
__global__ __launch_bounds__(256) void transpose_x(const float* __restrict__ x,
                                                   u16* __restrict__ xt) {
  const int b = blockIdx.z;
  const int t0 = blockIdx.x << 6;
  const int c0 = blockIdx.y << 6;
  const float* __restrict__ X = x + (size_t)b * (C_ * (size_t)T_);
  u16* __restrict__ Xt = xt + (size_t)b * (T_ * (size_t)C_);
  __shared__ float Ts[64][65];
  const int tid = threadIdx.x;
#pragma unroll
  for (int i = 0; i < 4; ++i) {
    const int e = tid + (i << 8);
    const int r = e >> 4, c4 = e & 15;
    const float4 v = *(const float4*)(X + (size_t)(c0 + r) * T_ + t0 + (c4 << 2));
    Ts[r][(c4 << 2) + 0] = v.x; Ts[r][(c4 << 2) + 1] = v.y;
    Ts[r][(c4 << 2) + 2] = v.z; Ts[r][(c4 << 2) + 3] = v.w;
  }
  __syncthreads();
#pragma unroll
  for (int i = 0; i < 2; ++i) {
    const int e = tid + (i << 8);
    const int tt = e >> 3, c8 = e & 7;
    u16x8 o;
#pragma unroll
    for (int j = 0; j < 8; ++j) o[j] = f2bf(Ts[(c8 << 3) + j][tt]);
    *(u16x8*)(Xt + (size_t)(t0 + tt) * C_ + c0 + (c8 << 3)) = o;
  }
}

// ------- Qt/Kt = Xt @ W^T -> [t][o] bf16 (Q scaled by 1/8), 64x64 tiles -----
__global__ __launch_bounds__(256) void gemm_qkt(const u16* __restrict__ xt,
                                                const float* __restrict__ wq,
                                                const float* __restrict__ wk,
                                                u16* __restrict__ qto,
                                                u16* __restrict__ kto) {
  const int which = blockIdx.z >> 2;
  const int b = blockIdx.z & 3;
  const float* __restrict__ W = which ? wk : wq;
  u16* __restrict__ Y = (which ? kto : qto) + (size_t)b * (T_ * (size_t)C_);
  const u16* __restrict__ A = xt + (size_t)b * (T_ * (size_t)C_);
  const float sc = which ? 1.0f : SCALE_;
  const int m0 = blockIdx.x << 6;  // t
  const int n0 = blockIdx.y << 6;  // o
  __shared__ u16 As[64][72];
  __shared__ u16 Bs[64][72];
  const int tid = threadIdx.x;
  const int w = tid >> 6, lane = tid & 63, lr = lane & 15, lq = lane >> 4;
  const int mw = (w >> 1) << 5, nw = (w & 1) << 5;
  f32x4 acc[2][2] = {};
  for (int k0 = 0; k0 < C_; k0 += 64) {
#pragma unroll
    for (int it = 0; it < 2; ++it) {
      const int e = tid + (it << 8);
      const int r = e >> 3, c8 = e & 7;
      *(u16x8*)&As[r][c8 << 3] =
          *(const u16x8*)(A + (size_t)(m0 + r) * C_ + k0 + (c8 << 3));
      const float* wr = W + (size_t)(n0 + r) * C_ + k0 + (c8 << 3);
      const float4 f0 = *(const float4*)wr;
      const float4 f1 = *(const float4*)(wr + 4);
      u16x8 o;
      o[0] = f2bf(f0.x); o[1] = f2bf(f0.y); o[2] = f2bf(f0.z); o[3] = f2bf(f0.w);
      o[4] = f2bf(f1.x); o[5] = f2bf(f1.y); o[6] = f2bf(f1.z); o[7] = f2bf(f1.w);
      *(u16x8*)&Bs[r][c8 << 3] = o;
    }
    __syncthreads();
#pragma unroll
    for (int kf = 0; kf < 2; ++kf) {
      const int ko = (kf << 5) + (lq << 3);
      s16x8 a[2], bb[2];
#pragma unroll
      for (int i = 0; i < 2; ++i) a[i] = *(const s16x8*)&As[mw + (i << 4) + lr][ko];
#pragma unroll
      for (int j = 0; j < 2; ++j) bb[j] = *(const s16x8*)&Bs[nw + (j << 4) + lr][ko];
#pragma unroll
      for (int i = 0; i < 2; ++i)
#pragma unroll
        for (int j = 0; j < 2; ++j) acc[i][j] = mfma16(a[i], bb[j], acc[i][j]);
    }
    __syncthreads();
  }
#pragma unroll
  for (int i = 0; i < 2; ++i) {
    const int row = mw + (i << 4) + (lq << 2);
#pragma unroll
    for (int j = 0; j < 2; ++j) {
      const int col = nw + (j << 4) + lr;
#pragma unroll
      for (int r = 0; r < 4; ++r)
        Y[(size_t)(m0 + row + r) * C_ + n0 + col] = f2bf(acc[i][j][r] * sc);
    }
  }
}

// ---------------- V = Wv @ X  -> [o][t] bf16, 64x64 tiles ----------------
__global__ __launch_bounds__(256) void gemm_v(const u16* __restrict__ xt,
                                              const float* __restrict__ wv,
                                              u16* __restrict__ vout) {
  const int b = blockIdx.z;
  const int n0 = blockIdx.x << 6;  // t
  const int m0 = blockIdx.y << 6;  // o
  const u16* __restrict__ Bg = xt + (size_t)b * (T_ * (size_t)C_);
  u16* __restrict__ Y = vout + (size_t)b * (C_ * (size_t)T_);
  __shared__ u16 As[64][72];
  __shared__ u16 Bs[64][72];
  const int tid = threadIdx.x;
  const int w = tid >> 6, lane = tid & 63, lr = lane & 15, lq = lane >> 4;
  const int mw = (w >> 1) << 5, nw = (w & 1) << 5;
  f32x4 acc[2][2] = {};
  for (int k0 = 0; k0 < C_; k0 += 64) {
#pragma unroll
    for (int it = 0; it < 2; ++it) {
      const int e = tid + (it << 8);
      const int r = e >> 3, c8 = e & 7;
      const float* wr = wv + (size_t)(m0 + r) * C_ + k0 + (c8 << 3);
      const float4 f0 = *(const float4*)wr;
      const float4 f1 = *(const float4*)(wr + 4);
      u16x8 o;
      o[0] = f2bf(f0.x); o[1] = f2bf(f0.y); o[2] = f2bf(f0.z); o[3] = f2bf(f0.w);
      o[4] = f2bf(f1.x); o[5] = f2bf(f1.y); o[6] = f2bf(f1.z); o[7] = f2bf(f1.w);
      *(u16x8*)&As[r][c8 << 3] = o;
      *(u16x8*)&Bs[r][c8 << 3] =
          *(const u16x8*)(Bg + (size_t)(n0 + r) * C_ + k0 + (c8 << 3));
    }
    __syncthreads();
#pragma unroll
    for (int kf = 0; kf < 2; ++kf) {
      const int ko = (kf << 5) + (lq << 3);
      s16x8 a[2], bb[2];
#pragma unroll
      for (int i = 0; i < 2; ++i) a[i] = *(const s16x8*)&As[mw + (i << 4) + lr][ko];
#pragma unroll
      for (int j = 0; j < 2; ++j) bb[j] = *(const s16x8*)&Bs[nw + (j << 4) + lr][ko];
#pragma unroll
      for (int i = 0; i < 2; ++i)
#pragma unroll
        for (int j = 0; j < 2; ++j) acc[i][j] = mfma16(a[i], bb[j], acc[i][j]);
    }
    __syncthreads();
  }
#pragma unroll
  for (int i = 0; i < 2; ++i) {
    const int row = mw + (i << 4) + (lq << 2);
#pragma unroll
    for (int j = 0; j < 2; ++j) {
      const int col = nw + (j << 4) + lr;
#pragma unroll
      for (int r = 0; r < 4; ++r)
        Y[(size_t)(m0 + row + r) * T_ + n0 + col] = f2bf(acc[i][j][r]);
    }
  }
}

// ---------------- vsum[b][g][d] = sum_t V ----------------
__global__ __launch_bounds__(256) void vsum_k(const u16* __restrict__ v,
                                              float* __restrict__ vsum) {
  const int bg = blockIdx.x;  // b*8+g
  const int tid = threadIdx.x;
  const int d = tid >> 2, part = tid & 3;
  const u16* __restrict__ Vr =
      v + ((size_t)(bg >> 3) * C_ + ((bg & 7) << 6) + d) * T_ + (part << 8);
  float s = 0.f;
  for (int t = 0; t < 256; t += 8) {
    const u16x8 x = *(const u16x8*)(Vr + t);
#pragma unroll
    for (int j = 0; j < 8; ++j) s += b2f(x[j]);
  }
  s += __shfl_down(s, 2, 64);
  s += __shfl_down(s, 1, 64);
  if (part == 0) vsum[(bg << 6) + d] = s;
}

// ---- pass 1: S^T = K·Q^T (permuted K rows), head-mix, exp, P bf16 + l/l2 ---
// block (q16, t128, b); wave w covers t-chunk tb*128+w*32. Permuted A rows
// (perm(m)=(m>>2)*8+(m&3), HW-validated in R8) give each lane q=lr and
// t = chunk + quad*8 + {0..7} CONTIGUOUS -> one u16x8 P store per g, and
// l/l2 reduce = 8 local adds + 2 shuffles per g.
__global__ __launch_bounds__(256, 4) void qk_mix(const u16* __restrict__ Qt,
                                                 const u16* __restrict__ Kt,
                                                 const float* __restrict__ wh,
                                                 u16* __restrict__ P,
                                                 float* __restrict__ lpart,
                                                 float* __restrict__ l2part) {
  const int qb = blockIdx.x;  // q /16
  const int tb = blockIdx.y;  // t /128
  const int b = blockIdx.z;
  const int tid = threadIdx.x;
  const int w = tid >> 6, lane = tid & 63;
  const int lr = lane & 15, quad = lane >> 4;
  const int q0 = qb << 4;
  const int bg0 = b << 3;

  __shared__ u16 Qs[16][522];

  {
    const u16* Qb = Qt + ((size_t)b * T_ + q0) * C_;
    for (int i = tid; i < 1024; i += 256) {
      const int r = i >> 6, c8 = i & 63;
      *(u16x8*)&Qs[r][c8 << 3] = *(const u16x8*)(Qb + (size_t)r * C_ + (c8 << 3));
    }
  }
  __syncthreads();

  const int tchunk = (tb << 7) + (w << 5);
  const int tp = ((lr >> 2) << 3) + (lr & 3);  // permuted row for a0; a1 = +4
  const u16* __restrict__ K0 =
      Kt + ((size_t)b * T_ + tchunk + tp) * C_ + (quad << 3);
  const u16* __restrict__ K1 = K0 + 4 * C_;
  const u16* __restrict__ Qrow = &Qs[lr][quad << 3];

  f32x4 m[8][2] = {};
#pragma unroll 2
  for (int h = 0; h < 8; ++h) {
    f32x4 a0 = {0.f, 0.f, 0.f, 0.f}, a1 = {0.f, 0.f, 0.f, 0.f};
#pragma unroll
    for (int kf = 0; kf < 2; ++kf) {
      const int co = (h << 6) + (kf << 5);
      const s16x8 qf = *(const s16x8*)(Qrow + co);
      const s16x8 k0 = *(const s16x8*)(K0 + co);
      const s16x8 k1 = *(const s16x8*)(K1 + co);
      a0 = mfma16(k0, qf, a0);
      a1 = mfma16(k1, qf, a1);
    }
#pragma unroll
    for (int g = 0; g < 8; ++g) {
      const float wgh = wh[(g << 3) + h];  // uniform -> SGPR
      m[g][0] += a0 * wgh;
      m[g][1] += a1 * wgh;
    }
  }
  // lane's t slots: m[g][0] -> tchunk+quad*8+{0..3}, m[g][1] -> +{4..7}; q=q0+lr
  const size_t pq = ((size_t)q0 + lr) * 1024 + tchunk + (quad << 3);
#pragma unroll
  for (int g = 0; g < 8; ++g) {
    f32x4 e0, e1;
#pragma unroll
    for (int k = 0; k < 4; ++k) {
      e0[k] = __expf(m[g][0][k]);
      e1[k] = __expf(m[g][1][k]);
    }
    u16x8 o;
#pragma unroll
    for (int k = 0; k < 4; ++k) {
      o[k] = f2bf(e0[k]);
      o[k + 4] = f2bf(e1[k]);
    }
    *(u16x8*)(P + (((size_t)(bg0 + g)) << 20) + pq) = o;
    float l = e0[0] + e0[1] + e0[2] + e0[3] + e1[0] + e1[1] + e1[2] + e1[3];
    float l2 = e0[0] * e0[0] + e0[1] * e0[1] + e0[2] * e0[2] + e0[3] * e0[3] +
               e1[0] * e1[0] + e1[1] * e1[1] + e1[2] * e1[2] + e1[3] * e1[3];
    l += __shfl_xor(l, 16, 64);
    l += __shfl_xor(l, 32, 64);
    l2 += __shfl_xor(l2, 16, 64);
    l2 += __shfl_xor(l2, 32, 64);
    if (quad == 0) {
      const size_t idx =
          ((((size_t)(bg0 + g)) << 10) + q0 + lr) * 32 + (tb << 2) + w;
      lpart[idx] = l;
      l2part[idx] = l2;
    }
  }
}

// ---- reduce l partials: linv[bg][q], and alpha/beta' per (b,g) -> ab ----
__global__ __launch_bounds__(256) void reduce_l(const float* __restrict__ lpart,
                                                const float* __restrict__ l2part,
                                                const float* __restrict__ gamma,
                                                const float* __restrict__ beta,
                                                float* __restrict__ linv,
                                                float* __restrict__ ab) {
  const int bg = blockIdx.x;
  const int g = bg & 7;
  const int tid = threadIdx.x;
  float ssq = 0.f;
#pragma unroll
  for (int k = 0; k < 4; ++k) {
    const int q = (tid << 2) + k;
    const float* lp = lpart + (((size_t)bg << 10) + q) * 32;
    const float* l2p = l2part + (((size_t)bg << 10) + q) * 32;
    float l = 0.f, l2 = 0.f;
#pragma unroll
    for (int j = 0; j < 32; j += 4) {
      const f32x4 a = *(const f32x4*)(lp + j);
      const f32x4 c = *(const f32x4*)(l2p + j);
      l += a[0] + a[1] + a[2] + a[3];
      l2 += c[0] + c[1] + c[2] + c[3];
    }
    linv[((size_t)bg << 10) + q] = 1.f / l;
    ssq += l2 / (l * l);
  }
#pragma unroll
  for (int off = 32; off; off >>= 1) ssq += __shfl_xor(ssq, off, 64);
  __shared__ float red[4];
  if ((tid & 63) == 0) red[tid >> 6] = ssq;
  __syncthreads();
  if (tid == 0) {
    const float s = red[0] + red[1] + red[2] + red[3];
    const float mean = 0.0009765625f;
    const float var = s * (1.f / 1048576.f) - mean * mean;
    const float al = gamma[g] * rsqrtf(var + EPS_);
    ab[bg * 2] = al;
    ab[bg * 2 + 1] = beta[g] - al * mean;
  }
}

// ---- pass 2: O[bg][q][d] = (P[q][:] @ V[d][:]^T) * linv[q]  (64q x 64d) ----
__global__ __launch_bounds__(256) void gemm_pv(const u16* __restrict__ P,
                                               const u16* __restrict__ v,
                                               const float* __restrict__ linv,
                                               u16* __restrict__ O) {
  const int qt0 = blockIdx.x << 6;
  const int bg = blockIdx.y;
  const u16* __restrict__ A = P + (((size_t)bg << 10) + qt0) * 1024;
  const u16* __restrict__ Vg =
      v + ((size_t)(bg >> 3) * C_ + ((bg & 7) << 6)) * 1024;
  __shared__ u16 Ps[64][40];
  __shared__ u16 Vs[64][40];
  __shared__ float lT[64];
  const int tid = threadIdx.x;
  const int w = tid >> 6, lane = tid & 63, lr = lane & 15, quad = lane >> 4;
  if (tid < 64) lT[tid] = linv[((size_t)bg << 10) + qt0 + tid];
  f32x4 acc[4] = {};
  const int r = tid >> 2, c4 = tid & 3;
#pragma unroll 1
  for (int k0 = 0; k0 < 1024; k0 += 32) {
    __syncthreads();
    *(u16x8*)&Ps[r][c4 << 3] =
        *(const u16x8*)(A + (size_t)r * 1024 + k0 + (c4 << 3));
    *(u16x8*)&Vs[r][c4 << 3] =
        *(const u16x8*)(Vg + (size_t)r * 1024 + k0 + (c4 << 3));
    __syncthreads();
    const s16x8 a = *(const s16x8*)&Ps[(w << 4) + lr][quad << 3];
#pragma unroll
    for (int j = 0; j < 4; ++j) {
      const s16x8 bb = *(const s16x8*)&Vs[(j << 4) + lr][quad << 3];
      acc[j] = mfma16(a, bb, acc[j]);
    }
  }
#pragma unroll
  for (int j = 0; j < 4; ++j) {
    const int d = (j << 4) + lr;
#pragma unroll
    for (int rr = 0; rr < 4; ++rr) {
      const int q = (w << 4) + (quad << 2) + rr;
      O[(((size_t)bg << 10) + qt0 + q) * 64 + d] = f2bf(acc[j][rr] * lT[q]);
    }
  }
}

// -------- bias2[b][g][o] = bp[o] + bt2[b,g] * sum_d vsum[b,g,d]*wsum[o][d]
__global__ __launch_bounds__(256) void bias2_k(const float* __restrict__ wp,
                                               const float* __restrict__ bp,
                                               const float* __restrict__ ab,
                                               const float* __restrict__ vsum,
                                               float* __restrict__ bias2) {
  const int idx = (blockIdx.x << 8) + threadIdx.x;  // 16384 = B*8*512
  const int b = idx >> 12, g = (idx >> 9) & 7, o = idx & 511;
  const float bt2 = ab[(((b << 3) + g) << 1) + 1];
  const float* wr = wp + (size_t)o * C_;
  const float* vs = vsum + (((b << 3) + g) << 6);
  float acc = 0.f;
#pragma unroll
  for (int d = 0; d < 64; d += 4) {
    const float4 vv4 = *(const float4*)(vs + d);
    float4 ws4 = {0.f, 0.f, 0.f, 0.f};
#pragma unroll
    for (int j = 0; j < 8; ++j) {
      const float4 wv4 = *(const float4*)(wr + (j << 6) + d);
      ws4.x += wv4.x; ws4.y += wv4.y; ws4.z += wv4.z; ws4.w += wv4.w;
    }
    acc += ws4.x * vv4.x + ws4.y * vv4.y + ws4.z * vv4.z + ws4.w * vv4.w;
  }
  bias2[(((b << 3) + g) << 9) + o] = bp[o] + bt2 * acc;
}

// ------- y = al[b,g(t)]*(Mnorm @ Wp^T) + bias2[b][g(t)][o], 64x64 tiles ----
__global__ __launch_bounds__(256) void gemm_proj(const u16* __restrict__ O,
                                                 const float* __restrict__ wp,
                                                 const float* __restrict__ ab,
                                                 const float* __restrict__ bias2,
                                                 float* __restrict__ y) {
  const int b = blockIdx.z;
  const int m0 = blockIdx.y << 6;  // o
  const int n0 = blockIdx.x << 6;  // t
  const int gidx = blockIdx.x >> 1;
  const u16* __restrict__ Ob = O + (size_t)b * (8 * T_ * 64);
  __shared__ u16 As[64][72];
  __shared__ u16 Bs[64][72];
  const int tid = threadIdx.x;
  const int w = tid >> 6, lane = tid & 63, lr = lane & 15, lq = lane >> 4;
  const int mw = (w >> 1) << 5, nw = (w & 1) << 5;
  f32x4 acc[2][2] = {};
  for (int k0 = 0; k0 < C_; k0 += 64) {
#pragma unroll
    for (int it = 0; it < 2; ++it) {
      const int e = tid + (it << 8);
      const int r = e >> 3, c8 = e & 7;
      const float* wr = wp + (size_t)(m0 + r) * C_ + k0 + (c8 << 3);
      const float4 f0 = *(const float4*)wr;
      const float4 f1 = *(const float4*)(wr + 4);
      u16x8 o;
      o[0] = f2bf(f0.x); o[1] = f2bf(f0.y); o[2] = f2bf(f0.z); o[3] = f2bf(f0.w);
      o[4] = f2bf(f1.x); o[5] = f2bf(f1.y); o[6] = f2bf(f1.z); o[7] = f2bf(f1.w);
      *(u16x8*)&As[r][c8 << 3] = o;
      const int t = n0 + r;
      const int c = k0 + (c8 << 3);
      *(u16x8*)&Bs[r][c8 << 3] =
          *(const u16x8*)(Ob + (size_t)(t >> 7) * (T_ * 64) +
                          (size_t)(((t & 127) << 3) + (c >> 6)) * 64 + (c & 63));
    }
    __syncthreads();
#pragma unroll
    for (int kf = 0; kf < 2; ++kf) {
      const int ko = (kf << 5) + (lq << 3);
      s16x8 a[2], bb[2];
#pragma unroll
      for (int i = 0; i < 2; ++i) a[i] = *(const s16x8*)&As[mw + (i << 4) + lr][ko];
#pragma unroll
      for (int j = 0; j < 2; ++j) bb[j] = *(const s16x8*)&Bs[nw + (j << 4) + lr][ko];
#pragma unroll
      for (int i = 0; i < 2; ++i)
#pragma unroll
        for (int j = 0; j < 2; ++j) acc[i][j] = mfma16(a[i], bb[j], acc[i][j]);
    }
    __syncthreads();
  }
  const float al = ab[(((b << 3) + gidx) << 1)];
  const float* __restrict__ b2 = bias2 + (((b << 3) + gidx) << 9);
#pragma unroll
  for (int i = 0; i < 2; ++i) {
    const int row = mw + (i << 4) + (lq << 2);
#pragma unroll
    for (int j = 0; j < 2; ++j) {
      const int col = nw + (j << 4) + lr;
#pragma unroll
      for (int r = 0; r < 4; ++r)
        y[(size_t)b * (C_ * (size_t)T_) + (size_t)(m0 + row + r) * T_ + n0 + col] =
            acc[i][j][r] * al + b2[m0 + row + r];
    }
  }
}

extern "C" void kernel_launch(void* const* d_in, const int* in_sizes, int n_in,
                              void* d_out, int out_size, void* d_ws,
                              size_t ws_size, hipStream_t stream) {
  const float* x = (const float*)d_in[0];
  const float* wq = (const float*)d_in[1];
  const float* wk = (const float*)d_in[2];
  const float* wv = (const float*)d_in[3];
  const float* wh = (const float*)d_in[4];
  const float* gm = (const float*)d_in[5];
  const float* bt = (const float*)d_in[6];
  const float* wp = (const float*)d_in[7];
  const float* bp = (const float*)d_in[8];
  float* y = (float*)d_out;
  char* wsb = (char*)d_ws;

  u16* Qt = (u16*)(wsb + QT_OFF);
  u16* Kt = (u16*)(wsb + KT_OFF);
  u16* V = (u16*)(wsb + V_OFF);
  u16* Xt = (u16*)(wsb + XT_OFF);
  u16* Og = (u16*)(wsb + O_OFF);
  float* ab = (float*)(wsb + AB_OFF);
  float* vsum = (float*)(wsb + VSUM_OFF);
  float* bias2 = (float*)(wsb + BIAS2_OFF);
  u16* P = (u16*)(wsb + P_OFF);
  float* lpart = (float*)(wsb + LP_OFF);
  float* l2part = (float*)(wsb + L2P_OFF);
  float* linv = (float*)(wsb + LINV_OFF);

  transpose_x<<<dim3(16, 8, 4), 256, 0, stream>>>(x, Xt);
  gemm_qkt<<<dim3(16, 8, 8), 256, 0, stream>>>(Xt, wq, wk, Qt, Kt);
  gemm_v<<<dim3(16, 8, 4), 256, 0, stream>>>(Xt, wv, V);
  vsum_k<<<dim3(32), 256, 0, stream>>>(V, vsum);
  qk_mix<<<dim3(64, 8, 4), 256, 0, stream>>>(Qt, Kt, wh, P, lpart, l2part);
  reduce_l<<<dim3(32), 256, 0, stream>>>(lpart, l2part, gm, bt, linv, ab);
  gemm_pv<<<dim3(16, 32), 256, 0, stream>>>(P, V, linv, Og);
  bias2_k<<<dim3(64), 256, 0, stream>>>(wp, bp, ab, vsum, bias2);
  gemm_proj<<<dim3(16, 8, 4), 256, 0, stream>>>(Og, wp, ab, bias2, y);
}